// Round 1
// baseline (146.185 us; speedup 1.0000x reference)
//
#include <hip/hip_runtime.h>

typedef unsigned short u16;
typedef unsigned int   u32;
typedef __attribute__((ext_vector_type(8))) short bf8;   // 8 x bf16 (4 VGPRs)
typedef __attribute__((ext_vector_type(4))) float f4;    // 4 x f32 accumulator

#define MFMA(a,b,c) __builtin_amdgcn_mfma_f32_16x16x32_bf16(a,b,c,0,0,0)

__device__ __forceinline__ u16 f2bf(float f){
  u32 u = __float_as_uint(f);
  u += 0x7fffu + ((u >> 16) & 1u);          // RNE
  return (u16)(u >> 16);
}
__device__ __forceinline__ float bf2f(u16 h){ return __uint_as_float(((u32)h) << 16); }
__device__ __forceinline__ u32 pk2(float a, float b){ return (u32)f2bf(a) | ((u32)f2bf(b) << 16); }

// ---- swizzled LDS bf16 matrix helpers: row-major, XOR (row&7) into 16B-chunk bits ----
__device__ __forceinline__ bf8 ldsFrag(const char* m, int row0, int k0, int pitch){
  int l = threadIdx.x & 63;
  int r = row0 + (l & 15);
  int kb = ((k0 + ((l >> 4) << 3)) << 1) ^ ((r & 7) << 4);
  return *(const bf8*)(m + r * pitch + kb);
}
__device__ __forceinline__ float ldsGet(const char* m, int row, int col, int pitch){
  int kb = (col << 1) ^ ((row & 7) << 4);
  return bf2f(*(const u16*)(m + row * pitch + kb));
}
__device__ __forceinline__ void ldsPut(char* m, int row, int col, int pitch, u16 v){
  int kb = (col << 1) ^ ((row & 7) << 4);
  *(u16*)(m + row * pitch + kb) = v;
}

// =====================================================================
// K0: zero logits
// =====================================================================
__global__ void k_zero(float* __restrict__ p){
  int i = blockIdx.x * 256 + threadIdx.x;
  if (i < 16384) p[i] = 0.f;
}

// =====================================================================
// K1: 1x1 conv GEMM (C[d][hw] = sum_c w_dr[d][c] * x[b][c][hw]) + BN1 + ReLU,
//     then center over d, scale 1/sqrt(128), write W [b][hw][d] and WT [b][d][hw] (bf16)
// grid 256 = 64 b x 4 hw-blocks of 64; 512 threads (8 waves, 4x2 tiles of 32x32)
// =====================================================================
__global__ __launch_bounds__(512) void k_conv(
    const float* __restrict__ x, const float* __restrict__ wdr, const float* __restrict__ bdr,
    const float* __restrict__ g1, const float* __restrict__ be1,
    const float* __restrict__ m1, const float* __restrict__ v1,
    u16* __restrict__ Wg, u16* __restrict__ WTg){
  __shared__ union {
    struct { char A[16384]; char Bt[8192]; } s;           // A: [128][64] bf16 swz pitch128; Bt: [64][64] bf16 swz pitch128
    struct { float y[128 * 65]; float musum[8 * 64]; float mu[64]; } e;
  } sm;
  int t = threadIdx.x;
  int b = blockIdx.x >> 2, hw0 = (blockIdx.x & 3) * 64;
  int w = t >> 6, l = t & 63;
  int rows0 = (w >> 1) * 32, cols0 = (w & 1) * 32;
  int lc = l & 15, lr = (l >> 4) * 4;

  const f4 fz = {0.f, 0.f, 0.f, 0.f};
  f4 acc[2][2];
  acc[0][0] = fz; acc[0][1] = fz; acc[1][0] = fz; acc[1][1] = fz;

  int ad = t >> 2;                 // A-load row d (0..127)
  int ac = (t & 3) * 16;           // A-load col base
  const float* xb = x + (size_t)b * 1024 * 256 + hw0;

  for (int kk = 0; kk < 16; ++kk) {
    int c0 = kk * 64;
    // A-tile: w_dr[ad][c0+ac .. +15]
    #pragma unroll
    for (int j = 0; j < 4; ++j) {
      float4 vv = *(const float4*)(wdr + (size_t)ad * 1024 + c0 + ac + j * 4);
      int cb = ((ac + j * 4) * 2) ^ ((ad & 7) << 4);
      *(u32*)(sm.s.A + ad * 128 + cb)     = pk2(vv.x, vv.y);
      *(u32*)(sm.s.A + ad * 128 + cb + 4) = pk2(vv.z, vv.w);
    }
    // B-tile: x[b][c][hw] -> LDS [hw][c] (transpose-scatter)
    #pragma unroll
    for (int j2 = 0; j2 < 4; ++j2) {
      int cc = w * 8 + j2 * 2;
      float v0 = xb[(size_t)(c0 + cc) * 256 + l];
      float v1x = xb[(size_t)(c0 + cc + 1) * 256 + l];
      int cb = (cc * 2) ^ ((l & 7) << 4);
      *(u32*)(sm.s.Bt + l * 128 + cb) = pk2(v0, v1x);
    }
    __syncthreads();
    #pragma unroll
    for (int ks = 0; ks < 2; ++ks) {
      int k0 = ks * 32;
      bf8 a0 = ldsFrag(sm.s.A, rows0,      k0, 128);
      bf8 a1 = ldsFrag(sm.s.A, rows0 + 16, k0, 128);
      bf8 b0 = ldsFrag(sm.s.Bt, cols0,      k0, 128);
      bf8 b1 = ldsFrag(sm.s.Bt, cols0 + 16, k0, 128);
      acc[0][0] = MFMA(a0, b0, acc[0][0]);
      acc[0][1] = MFMA(a0, b1, acc[0][1]);
      acc[1][0] = MFMA(a1, b0, acc[1][0]);
      acc[1][1] = MFMA(a1, b1, acc[1][1]);
    }
    __syncthreads();
  }
  // epilogue: BN1 + ReLU -> Ystage f32 (pitch 65 floats)
  #pragma unroll
  for (int i = 0; i < 2; ++i)
    #pragma unroll
    for (int r = 0; r < 4; ++r) {
      int d = rows0 + i * 16 + lr + r;
      float s1 = g1[d] * rsqrtf(v1[d] + 1e-5f);
      float t1 = (bdr[d] - m1[d]) * s1 + be1[d];
      #pragma unroll
      for (int j = 0; j < 2; ++j) {
        int hwl = cols0 + j * 16 + lc;
        sm.e.y[d * 65 + hwl] = fmaxf(acc[i][j][r] * s1 + t1, 0.f);
      }
    }
  __syncthreads();
  { // column means over d (128)
    int part = t >> 6, col = t & 63;
    float s = 0.f;
    #pragma unroll
    for (int i2 = 0; i2 < 16; ++i2) s += sm.e.y[(part * 16 + i2) * 65 + col];
    sm.e.musum[part * 64 + col] = s;
  }
  __syncthreads();
  if (t < 64) {
    float m = 0.f;
    #pragma unroll
    for (int p = 0; p < 8; ++p) m += sm.e.musum[p * 64 + t];
    sm.e.mu[t] = m * (1.0f / 128.0f);
  }
  __syncthreads();
  const float ISM = 0.08838834764831845f;   // 1/sqrt(128)
  { // W [b][hw][d]
    int hwl = t >> 3, dc = (t & 7) * 16;
    float muv = sm.e.mu[hwl];
    u32 q[8];
    #pragma unroll
    for (int jj = 0; jj < 8; ++jj) {
      float a = (sm.e.y[(dc + 2 * jj)     * 65 + hwl] - muv) * ISM;
      float c = (sm.e.y[(dc + 2 * jj + 1) * 65 + hwl] - muv) * ISM;
      q[jj] = pk2(a, c);
    }
    uint4* d4 = (uint4*)(Wg + ((size_t)(b * 256 + hw0 + hwl) * 128 + dc));
    d4[0] = make_uint4(q[0], q[1], q[2], q[3]);
    d4[1] = make_uint4(q[4], q[5], q[6], q[7]);
  }
  { // WT [b][d][hw]
    int d = t >> 2, hc = (t & 3) * 16;
    u32 q[8];
    #pragma unroll
    for (int jj = 0; jj < 8; ++jj) {
      int h0 = hc + 2 * jj, h1 = hc + 2 * jj + 1;
      float a = (sm.e.y[d * 65 + h0] - sm.e.mu[h0]) * ISM;
      float c = (sm.e.y[d * 65 + h1] - sm.e.mu[h1]) * ISM;
      q[jj] = pk2(a, c);
    }
    uint4* d4 = (uint4*)(WTg + ((size_t)(b * 128 + d) * 256 + hw0 + hc));
    d4[0] = make_uint4(q[0], q[1], q[2], q[3]);
    d4[1] = make_uint4(q[4], q[5], q[6], q[7]);
  }
}

// =====================================================================
// K3: per-batch Gram (G = WT@WT^T / normA) + full Newton-Schulz chain in LDS (small space)
// 64 WGs x 512 threads; dynamic LDS = 5 x 32KB slots = 160KB
// =====================================================================
__device__ void mm128(const char* A, const char* B, char* D,
                      const char* M1, float c1, const char* M2, float c2, float sa){
  int t = threadIdx.x, w = t >> 6, l = t & 63;
  int r0 = (w >> 1) * 32, c0 = (w & 1) * 64;
  int lc = l & 15, lr = (l >> 4) * 4;
  const f4 fz = {0.f, 0.f, 0.f, 0.f};
  f4 acc[2][4];
  #pragma unroll
  for (int i = 0; i < 2; ++i)
    #pragma unroll
    for (int j = 0; j < 4; ++j) acc[i][j] = fz;
  #pragma unroll
  for (int kk = 0; kk < 4; ++kk) {
    int k0 = kk * 32;
    bf8 a0 = ldsFrag(A, r0,      k0, 256);
    bf8 a1 = ldsFrag(A, r0 + 16, k0, 256);
    bf8 b0 = ldsFrag(B, c0,      k0, 256);
    bf8 b1 = ldsFrag(B, c0 + 16, k0, 256);
    bf8 b2 = ldsFrag(B, c0 + 32, k0, 256);
    bf8 b3 = ldsFrag(B, c0 + 48, k0, 256);
    acc[0][0] = MFMA(a0, b0, acc[0][0]); acc[0][1] = MFMA(a0, b1, acc[0][1]);
    acc[0][2] = MFMA(a0, b2, acc[0][2]); acc[0][3] = MFMA(a0, b3, acc[0][3]);
    acc[1][0] = MFMA(a1, b0, acc[1][0]); acc[1][1] = MFMA(a1, b1, acc[1][1]);
    acc[1][2] = MFMA(a1, b2, acc[1][2]); acc[1][3] = MFMA(a1, b3, acc[1][3]);
  }
  #pragma unroll
  for (int i = 0; i < 2; ++i)
    #pragma unroll
    for (int j = 0; j < 4; ++j)
      #pragma unroll
      for (int r = 0; r < 4; ++r) {
        int row = r0 + i * 16 + lr + r, col = c0 + j * 16 + lc;
        float v = sa * acc[i][j][r];
        if (M1) v += c1 * ldsGet(M1, row, col, 256);
        if (M2) v += c2 * ldsGet(M2, row, col, 256);
        acc[i][j][r] = v;
      }
  __syncthreads();
  #pragma unroll
  for (int i = 0; i < 2; ++i)
    #pragma unroll
    for (int j = 0; j < 4; ++j)
      #pragma unroll
      for (int r = 0; r < 4; ++r) {
        int row = r0 + i * 16 + lr + r, col = c0 + j * 16 + lc;
        ldsPut(D, row, col, 256, f2bf(acc[i][j][r]));
      }
  __syncthreads();
}

extern __shared__ char smns[];
__global__ __launch_bounds__(512) void k_ns(const u16* __restrict__ WT,
                                            u16* __restrict__ yf, float* __restrict__ normAg){
  int b = blockIdx.x, t = threadIdx.x;
  char* G = smns;
  char* Y = smns + 32768;
  char* Z = smns + 65536;
  char* T = smns + 98304;
  char* P = smns + 131072;
  char* WTl = smns + 32768;                 // [128][512B] swz, overlays Y+Z during Gram
  float* trp = (float*)(smns + 131072);     // overlays P during Gram

  { // load WT[b] swizzled
    const u16* src = WT + (size_t)b * 32768;
    int row = t >> 2, q = t & 3;
    #pragma unroll
    for (int j = 0; j < 8; ++j) {
      int c16 = q + j * 4;
      bf8 v = *(const bf8*)(src + row * 256 + c16 * 8);
      int ph = c16 ^ (row & 7);
      *(bf8*)(WTl + row * 512 + ph * 16) = v;
    }
  }
  if (t == 0) *trp = 0.f;
  __syncthreads();

  int w = t >> 6, l = t & 63;
  int r0 = (w >> 1) * 32, c0 = (w & 1) * 64;
  int lc = l & 15, lr = (l >> 4) * 4;
  const f4 fz = {0.f, 0.f, 0.f, 0.f};
  f4 acc[2][4];
  #pragma unroll
  for (int i = 0; i < 2; ++i)
    #pragma unroll
    for (int j = 0; j < 4; ++j) acc[i][j] = fz;
  #pragma unroll
  for (int kk = 0; kk < 8; ++kk) {          // K = 256 over hw
    int k0 = kk * 32;
    bf8 a0 = ldsFrag(WTl, r0,      k0, 512);
    bf8 a1 = ldsFrag(WTl, r0 + 16, k0, 512);
    bf8 b0 = ldsFrag(WTl, c0,      k0, 512);
    bf8 b1 = ldsFrag(WTl, c0 + 16, k0, 512);
    bf8 b2 = ldsFrag(WTl, c0 + 32, k0, 512);
    bf8 b3 = ldsFrag(WTl, c0 + 48, k0, 512);
    acc[0][0] = MFMA(a0, b0, acc[0][0]); acc[0][1] = MFMA(a0, b1, acc[0][1]);
    acc[0][2] = MFMA(a0, b2, acc[0][2]); acc[0][3] = MFMA(a0, b3, acc[0][3]);
    acc[1][0] = MFMA(a1, b0, acc[1][0]); acc[1][1] = MFMA(a1, b1, acc[1][1]);
    acc[1][2] = MFMA(a1, b2, acc[1][2]); acc[1][3] = MFMA(a1, b3, acc[1][3]);
  }
  // trace(Gw)
  float tp = 0.f;
  #pragma unroll
  for (int i = 0; i < 2; ++i)
    #pragma unroll
    for (int j = 0; j < 4; ++j)
      #pragma unroll
      for (int r = 0; r < 4; ++r) {
        int row = r0 + i * 16 + lr + r, col = c0 + j * 16 + lc;
        if (row == col) tp += acc[i][j][r];
      }
  #pragma unroll
  for (int off = 32; off > 0; off >>= 1) tp += __shfl_down(tp, off);
  if (l == 0) atomicAdd(trp, tp);
  __syncthreads();
  float normA = fmaxf(*trp / 3.0f, 1e-12f);
  if (t == 0) normAg[b] = normA;
  float inv = 1.0f / normA;
  // write G = Gw/normA
  #pragma unroll
  for (int i = 0; i < 2; ++i)
    #pragma unroll
    for (int j = 0; j < 4; ++j)
      #pragma unroll
      for (int r = 0; r < 4; ++r) {
        int row = r0 + i * 16 + lr + r, col = c0 + j * 16 + lc;
        ldsPut(G, row, col, 256, f2bf(acc[i][j][r] * inv));
      }
  __syncthreads();
  { // init Y = 1.5I - 0.5G ; Z = -0.5I (overwrites WTl)
    int row = t >> 2, cb = (t & 3) * 32;
    for (int c = cb; c < cb + 32; ++c) {
      float g = ldsGet(G, row, c, 256);
      ldsPut(Y, row, c, 256, f2bf((row == c ? 1.5f : 0.f) - 0.5f * g));
      ldsPut(Z, row, c, 256, (row == c) ? f2bf(-0.5f) : (u16)0);
    }
  }
  __syncthreads();
  float z0 = 1.5f;
  for (int it = 0; it < 4; ++it) {
    mm128(Z, G, P, nullptr, 0.f, nullptr, 0.f, 1.0f);        // P = Z@G
    mm128(P, Y, T, Y, -0.5f * z0, nullptr, 0.f, -0.5f);      // T = -0.5 P@Y - 0.5 z0 Y
    if (it < 3)
      mm128(T, P, Z, Z, 1.5f, T, z0, 1.0f);                  // Z = T@P + 1.5Z + z0 T
    mm128(Y, G, P, nullptr, 0.f, nullptr, 0.f, 1.0f);        // P = Y@G
    mm128(P, T, Y, Y, 1.5f, nullptr, 0.f, 1.0f);             // Y = P@T + 1.5Y
    z0 *= 1.5f;
  }
  { // write yf[b] (unswizzled row-major)
    int row = t >> 2, q = t & 3;
    u16* dst = yf + (size_t)b * 16384 + row * 128;
    #pragma unroll
    for (int j = 0; j < 4; ++j) {
      int c16 = q + j * 4;
      int ph = c16 ^ (row & 7);
      *(bf8*)(dst + c16 * 8) = *(const bf8*)(Y + row * 256 + ph * 16);
    }
  }
}

// =====================================================================
// K4: S = W @ yf @ W^T / sqrt(normA), then BN2 row-affine + rc -> s_post bf16
// grid 256 = 64 b x 4 i-bands of 64; dyn LDS = 64K(W) + 32K(yf) + 16K(E) = 112K
// =====================================================================
extern __shared__ char smex[];
__global__ __launch_bounds__(512) void k_expand(
    const u16* __restrict__ Wg, const u16* __restrict__ yf, const float* __restrict__ normAg,
    const float* __restrict__ g2, const float* __restrict__ be2, const float* __restrict__ m2,
    const float* __restrict__ v2, const float* __restrict__ rcw, const float* __restrict__ rcb,
    u16* __restrict__ sp){
  int blk = blockIdx.x, b = blk >> 2, iband = blk & 3;
  char* Bm = smex;                 // W full [256][256B] swz
  char* Yl = smex + 65536;         // yf [128][256B] swz
  char* El = smex + 98304;         // E  [64][256B] swz
  int t = threadIdx.x;
  { const u16* src = Wg + (size_t)b * 32768;
    int row = t >> 1, q = t & 1;
    #pragma unroll
    for (int j = 0; j < 8; ++j) {
      int c16 = q + j * 2;
      bf8 v = *(const bf8*)(src + row * 128 + c16 * 8);
      int ph = c16 ^ (row & 7);
      *(bf8*)(Bm + row * 256 + ph * 16) = v;
    } }
  { const u16* src = yf + (size_t)b * 16384;
    int row = t >> 2, q = t & 3;
    #pragma unroll
    for (int j = 0; j < 4; ++j) {
      int c16 = q + j * 4;
      bf8 v = *(const bf8*)(src + row * 128 + c16 * 8);
      int ph = c16 ^ (row & 7);
      *(bf8*)(Yl + row * 256 + ph * 16) = v;
    } }
  __syncthreads();
  int w = t >> 6, l = t & 63, lc = l & 15, lr = (l >> 4) * 4;
  const f4 fz = {0.f, 0.f, 0.f, 0.f};
  { // E = W[band] @ yf  (64x128, K=128); waves 2x4, tiles 32x32
    int r0 = (w >> 2) * 32, c0 = (w & 3) * 32;
    f4 acc[2][2];
    acc[0][0] = fz; acc[0][1] = fz; acc[1][0] = fz; acc[1][1] = fz;
    #pragma unroll
    for (int kk = 0; kk < 4; ++kk) {
      int k0 = kk * 32;
      bf8 a0 = ldsFrag(Bm, iband * 64 + r0,      k0, 256);
      bf8 a1 = ldsFrag(Bm, iband * 64 + r0 + 16, k0, 256);
      bf8 b0 = ldsFrag(Yl, c0,      k0, 256);
      bf8 b1 = ldsFrag(Yl, c0 + 16, k0, 256);
      acc[0][0] = MFMA(a0, b0, acc[0][0]); acc[0][1] = MFMA(a0, b1, acc[0][1]);
      acc[1][0] = MFMA(a1, b0, acc[1][0]); acc[1][1] = MFMA(a1, b1, acc[1][1]);
    }
    #pragma unroll
    for (int i = 0; i < 2; ++i)
      #pragma unroll
      for (int j = 0; j < 2; ++j)
        #pragma unroll
        for (int r = 0; r < 4; ++r)
          ldsPut(El, r0 + i * 16 + lr + r, c0 + j * 16 + lc, 256, f2bf(acc[i][j][r]));
  }
  __syncthreads();
  { // S = E @ W^T (64x256, K=128); waves 2x4, tiles 32x64; fused affine epilogue
    float invs = rsqrtf(normAg[b]);
    int r0 = (w >> 2) * 32, c0 = (w & 3) * 64;
    f4 acc[2][4];
    #pragma unroll
    for (int i = 0; i < 2; ++i)
      #pragma unroll
      for (int j = 0; j < 4; ++j) acc[i][j] = fz;
    #pragma unroll
    for (int kk = 0; kk < 4; ++kk) {
      int k0 = kk * 32;
      bf8 a0 = ldsFrag(El, r0,      k0, 256);
      bf8 a1 = ldsFrag(El, r0 + 16, k0, 256);
      bf8 b0 = ldsFrag(Bm, c0,      k0, 256);
      bf8 b1 = ldsFrag(Bm, c0 + 16, k0, 256);
      bf8 b2 = ldsFrag(Bm, c0 + 32, k0, 256);
      bf8 b3 = ldsFrag(Bm, c0 + 48, k0, 256);
      acc[0][0] = MFMA(a0, b0, acc[0][0]); acc[0][1] = MFMA(a0, b1, acc[0][1]);
      acc[0][2] = MFMA(a0, b2, acc[0][2]); acc[0][3] = MFMA(a0, b3, acc[0][3]);
      acc[1][0] = MFMA(a1, b0, acc[1][0]); acc[1][1] = MFMA(a1, b1, acc[1][1]);
      acc[1][2] = MFMA(a1, b2, acc[1][2]); acc[1][3] = MFMA(a1, b3, acc[1][3]);
    }
    #pragma unroll
    for (int i = 0; i < 2; ++i)
      #pragma unroll
      for (int r = 0; r < 4; ++r) {
        int il = r0 + i * 16 + lr + r;
        int ig = iband * 64 + il;
        float bs = g2[ig] * rsqrtf(v2[ig] + 1e-5f);
        float al = bs * rcw[ig];
        float be = (be2[ig] - m2[ig] * bs) * rcw[ig] + rcb[ig];
        #pragma unroll
        for (int j = 0; j < 4; ++j) {
          int jg = c0 + j * 16 + lc;
          sp[(size_t)b * 65536 + ig * 256 + jg] = f2bf(acc[i][j][r] * invs * al + be);
        }
      }
  }
}

// =====================================================================
// K5: logits[b][r] += s_post[b][:] . fc_w[r][:]   (M=64, N=128/WG, K-chunk=256)
// grid 512 = 256 k-chunks x 2 r-halves; dyn LDS = 32K(A) + 64K(B) = 96K
// =====================================================================
extern __shared__ char smfc[];
__global__ __launch_bounds__(512) void k_fc(const u16* __restrict__ sp,
                                            const float* __restrict__ fcw,
                                            float* __restrict__ logits){
  int kc = blockIdx.x >> 1, rh = blockIdx.x & 1;
  int k0 = kc * 256, rbase = rh * 128;
  char* Al = smfc;           // [64][512B] swz
  char* Bl = smfc + 32768;   // [128][512B] swz
  int t = threadIdx.x;
  { // A: s_post rows b=64 x 256 k
    int row = t >> 3, q = t & 7;
    #pragma unroll
    for (int j = 0; j < 4; ++j) {
      int c16 = q + j * 8;
      bf8 v = *(const bf8*)(sp + (size_t)row * 65536 + k0 + c16 * 8);
      int ph = c16 ^ (row & 7);
      *(bf8*)(Al + row * 512 + ph * 16) = v;
    } }
  { // B: fc_w rows (rbase..+128) x 256 k, f32 -> bf16
    int lane16 = t & 15;
    #pragma unroll
    for (int pass = 0; pass < 4; ++pass) {
      int row = (t >> 4) + pass * 32;
      #pragma unroll
      for (int j = 0; j < 4; ++j) {
        int k = lane16 * 4 + j * 64;
        float4 v = *(const float4*)(fcw + (size_t)(rbase + row) * 65536 + k0 + k);
        int off = (k * 2) ^ ((row & 7) << 4);
        *(u32*)(Bl + row * 512 + off)     = pk2(v.x, v.y);
        *(u32*)(Bl + row * 512 + off + 4) = pk2(v.z, v.w);
      }
    } }
  __syncthreads();
  int w = t >> 6, l = t & 63, lc = l & 15, lr = (l >> 4) * 4;
  int r0 = (w >> 2) * 32, c0 = (w & 3) * 32;     // rows over b (64), cols over r-local (128)
  const f4 fz = {0.f, 0.f, 0.f, 0.f};
  f4 acc[2][2];
  acc[0][0] = fz; acc[0][1] = fz; acc[1][0] = fz; acc[1][1] = fz;
  #pragma unroll
  for (int kk = 0; kk < 8; ++kk) {
    int ks = kk * 32;
    bf8 a0 = ldsFrag(Al, r0,      ks, 512);
    bf8 a1 = ldsFrag(Al, r0 + 16, ks, 512);
    bf8 b0 = ldsFrag(Bl, c0,      ks, 512);
    bf8 b1 = ldsFrag(Bl, c0 + 16, ks, 512);
    acc[0][0] = MFMA(a0, b0, acc[0][0]); acc[0][1] = MFMA(a0, b1, acc[0][1]);
    acc[1][0] = MFMA(a1, b0, acc[1][0]); acc[1][1] = MFMA(a1, b1, acc[1][1]);
  }
  #pragma unroll
  for (int i = 0; i < 2; ++i)
    #pragma unroll
    for (int j = 0; j < 2; ++j)
      #pragma unroll
      for (int r = 0; r < 4; ++r) {
        int row = r0 + i * 16 + lr + r;
        int col = rbase + c0 + j * 16 + lc;
        atomicAdd(logits + row * 256 + col, acc[i][j][r]);
      }
}

// =====================================================================
// K7: out = x * sigmoid(logits + fc_b)
// =====================================================================
__global__ __launch_bounds__(256) void k_mul(const float* __restrict__ x,
                                             const float* __restrict__ logits,
                                             const float* __restrict__ fcb,
                                             float* __restrict__ out, int n4){
  int i = blockIdx.x * 256 + threadIdx.x;
  int str = gridDim.x * 256;
  for (; i < n4; i += str) {
    int e = i << 2;
    int b = e >> 18;            // 1024*256 elems per batch
    int hw = e & 255;
    float4 xv = ((const float4*)x)[i];
    float4 lg = *(const float4*)(logits + (b << 8) + hw);
    float4 fb = *(const float4*)(fcb + hw);
    float4 o;
    o.x = xv.x / (1.f + expf(-(lg.x + fb.x)));
    o.y = xv.y / (1.f + expf(-(lg.y + fb.y)));
    o.z = xv.z / (1.f + expf(-(lg.z + fb.z)));
    o.w = xv.w / (1.f + expf(-(lg.w + fb.w)));
    ((float4*)out)[i] = o;
  }
}

// =====================================================================
extern "C" void kernel_launch(void* const* d_in, const int* in_sizes, int n_in,
                              void* d_out, int out_size, void* d_ws, size_t ws_size,
                              hipStream_t stream){
  const float* x   = (const float*)d_in[0];
  const float* wdr = (const float*)d_in[1];
  const float* bdr = (const float*)d_in[2];
  const float* g1  = (const float*)d_in[3];
  const float* be1 = (const float*)d_in[4];
  const float* m1  = (const float*)d_in[5];
  const float* v1  = (const float*)d_in[6];
  const float* g2  = (const float*)d_in[7];
  const float* be2 = (const float*)d_in[8];
  const float* m2  = (const float*)d_in[9];
  const float* v2  = (const float*)d_in[10];
  const float* rcw = (const float*)d_in[11];
  const float* rcb = (const float*)d_in[12];
  const float* fcw = (const float*)d_in[13];
  const float* fcb = (const float*)d_in[14];
  float* out = (float*)d_out;
  char* ws = (char*)d_ws;
  u16*   Wg  = (u16*)(ws);                          // 4 MB  [64][256][128] bf16
  u16*   WTg = (u16*)(ws + (4u  << 20));            // 4 MB  [64][128][256] bf16
  u16*   yfg = (u16*)(ws + (8u  << 20));            // 2 MB  [64][128][128] bf16
  float* nAg = (float*)(ws + (10u << 20));          // 64 f32
  u16*   spg = (u16*)(ws + (11u << 20));            // 8 MB  [64][65536] bf16
  float* lgt = (float*)(ws + (20u << 20));          // 64 KB [64][256] f32

  hipFuncSetAttribute((const void*)k_ns,     hipFuncAttributeMaxDynamicSharedMemorySize, 163840);
  hipFuncSetAttribute((const void*)k_expand, hipFuncAttributeMaxDynamicSharedMemorySize, 114688);
  hipFuncSetAttribute((const void*)k_fc,     hipFuncAttributeMaxDynamicSharedMemorySize, 98304);

  k_zero  <<<64,   256, 0,      stream>>>(lgt);
  k_conv  <<<256,  512, 0,      stream>>>(x, wdr, bdr, g1, be1, m1, v1, Wg, WTg);
  k_ns    <<<64,   512, 163840, stream>>>(WTg, yfg, nAg);
  k_expand<<<256,  512, 114688, stream>>>(Wg, yfg, nAg, g2, be2, m2, v2, rcw, rcb, spg);
  k_fc    <<<512,  512, 98304,  stream>>>(spg, fcw, lgt);
  k_mul   <<<2048, 256, 0,      stream>>>(x, lgt, fcb, out, 4194304);
}

// Round 2
// 122.086 us; speedup vs baseline: 1.1974x; 1.1974x over previous
//
#include <hip/hip_runtime.h>

typedef unsigned short u16;
typedef unsigned int   u32;
typedef __attribute__((ext_vector_type(8))) short bf8;   // 8 x bf16 (4 VGPRs)
typedef __attribute__((ext_vector_type(4))) float f4;    // 4 x f32 accumulator
typedef __attribute__((ext_vector_type(16))) float f16f; // 16 x f32 accumulator (32x32 MFMA)

#define MFMA(a,b,c)   __builtin_amdgcn_mfma_f32_16x16x32_bf16(a,b,c,0,0,0)
#define MFMA32(a,b,c) __builtin_amdgcn_mfma_f32_32x32x16_bf16(a,b,c,0,0,0)

__device__ __forceinline__ u16 f2bf(float f){
  u32 u = __float_as_uint(f);
  u += 0x7fffu + ((u >> 16) & 1u);          // RNE
  return (u16)(u >> 16);
}
__device__ __forceinline__ float bf2f(u16 h){ return __uint_as_float(((u32)h) << 16); }
__device__ __forceinline__ u32 pk2(float a, float b){ return (u32)f2bf(a) | ((u32)f2bf(b) << 16); }

// ---- swizzled LDS bf16 matrix helpers (16x16 path, used by conv/expand/fc) ----
__device__ __forceinline__ bf8 ldsFrag(const char* m, int row0, int k0, int pitch){
  int l = threadIdx.x & 63;
  int r = row0 + (l & 15);
  int kb = ((k0 + ((l >> 4) << 3)) << 1) ^ ((r & 7) << 4);
  return *(const bf8*)(m + r * pitch + kb);
}
__device__ __forceinline__ void ldsPut(char* m, int row, int col, int pitch, u16 v){
  int kb = (col << 1) ^ ((row & 7) << 4);
  *(u16*)(m + row * pitch + kb) = v;
}

// ---- k_ns helpers: pitch-256B rows, chunk swizzle (row&15)<<4 ----
__device__ __forceinline__ bf8 fragNS(const char* m, int r0, int ks, int l){
  int r = r0 + (l & 31);
  int kb = ((ks << 5) + ((l >> 5) << 4)) ^ ((r & 15) << 4);
  return *(const bf8*)(m + r * 256 + kb);
}
__device__ __forceinline__ bf8 fragWT(const char* m, int r0, int ks, int l){
  int r = r0 + (l & 31);
  int kb = ((ks << 5) + ((l >> 5) << 4)) ^ ((r & 15) << 4);
  return *(const bf8*)(m + r * 512 + kb);
}
__device__ __forceinline__ char* nsAddr(char* m, int row, int col4){
  return m + row * 256 + ((col4 << 1) ^ ((row & 15) << 4));
}

// 64x64 matmul pass: acc += A[R0.., :] @ Bsym[C0.., :]^T  (B read row-major = B^T, symmetric)
__device__ __forceinline__ void mmPass(const char* A, const char* B, f16f (&acc)[2][2],
                                       int R0, int C0, int l){
  #pragma unroll
  for (int ks = 0; ks < 8; ++ks){
    bf8 a0 = fragNS(A, R0,      ks, l);
    bf8 a1 = fragNS(A, R0 + 32, ks, l);
    bf8 b0 = fragNS(B, C0,      ks, l);
    bf8 b1 = fragNS(B, C0 + 32, ks, l);
    acc[0][0] = MFMA32(a0, b0, acc[0][0]); acc[0][1] = MFMA32(a0, b1, acc[0][1]);
    acc[1][0] = MFMA32(a1, b0, acc[1][0]); acc[1][1] = MFMA32(a1, b1, acc[1][1]);
  }
}

// write 64x64 tile transposed (valid by symmetry), vectorized b64 stores.
// v = scale*acc (+ dval on diagonal) (+ 1.5*adv if adv)
__device__ __forceinline__ void writeTile(char* D, const f16f (&acc)[2][2], int R0, int C0, int l,
                                          float scale, float dval, const uint2* adv){
  #pragma unroll
  for (int ri = 0; ri < 2; ++ri)
  #pragma unroll
  for (int ci = 0; ci < 2; ++ci)
  #pragma unroll
  for (int g = 0; g < 4; ++g){
    int srow = C0 + ci * 32 + (l & 31);
    int scol = R0 + ri * 32 + g * 8 + ((l >> 5) << 2);
    float v[4];
    #pragma unroll
    for (int q = 0; q < 4; ++q){
      float x = scale * acc[ri][ci][g * 4 + q];
      x += ((scol + q) == srow) ? dval : 0.f;
      v[q] = x;
    }
    if (adv){
      uint2 ad = adv[(ri * 2 + ci) * 4 + g];
      v[0] += 1.5f * bf2f((u16)ad.x);
      v[1] += 1.5f * bf2f((u16)(ad.x >> 16));
      v[2] += 1.5f * bf2f((u16)ad.y);
      v[3] += 1.5f * bf2f((u16)(ad.y >> 16));
    }
    *(uint2*)nsAddr(D, srow, scol) = make_uint2(pk2(v[0], v[1]), pk2(v[2], v[3]));
  }
}

// =====================================================================
// K0: zero logits
// =====================================================================
__global__ void k_zero(float* __restrict__ p){
  int i = blockIdx.x * 256 + threadIdx.x;
  if (i < 16384) p[i] = 0.f;
}

// =====================================================================
// K1: 1x1 conv GEMM + BN1 + ReLU, center over d, scale 1/sqrt(128),
//     write W [b][hw][d] and WT [b][d][hw] (bf16)
// =====================================================================
__global__ __launch_bounds__(512) void k_conv(
    const float* __restrict__ x, const float* __restrict__ wdr, const float* __restrict__ bdr,
    const float* __restrict__ g1, const float* __restrict__ be1,
    const float* __restrict__ m1, const float* __restrict__ v1,
    u16* __restrict__ Wg, u16* __restrict__ WTg){
  __shared__ union {
    struct { char A[16384]; char Bt[8192]; } s;
    struct { float y[128 * 65]; float musum[8 * 64]; float mu[64]; } e;
  } sm;
  int t = threadIdx.x;
  int b = blockIdx.x >> 2, hw0 = (blockIdx.x & 3) * 64;
  int w = t >> 6, l = t & 63;
  int rows0 = (w >> 1) * 32, cols0 = (w & 1) * 32;
  int lc = l & 15, lr = (l >> 4) * 4;

  const f4 fz = {0.f, 0.f, 0.f, 0.f};
  f4 acc[2][2];
  acc[0][0] = fz; acc[0][1] = fz; acc[1][0] = fz; acc[1][1] = fz;

  int ad = t >> 2;
  int ac = (t & 3) * 16;
  const float* xb = x + (size_t)b * 1024 * 256 + hw0;

  for (int kk = 0; kk < 16; ++kk) {
    int c0 = kk * 64;
    #pragma unroll
    for (int j = 0; j < 4; ++j) {
      float4 vv = *(const float4*)(wdr + (size_t)ad * 1024 + c0 + ac + j * 4);
      int cb = ((ac + j * 4) * 2) ^ ((ad & 7) << 4);
      *(u32*)(sm.s.A + ad * 128 + cb)     = pk2(vv.x, vv.y);
      *(u32*)(sm.s.A + ad * 128 + cb + 4) = pk2(vv.z, vv.w);
    }
    #pragma unroll
    for (int j2 = 0; j2 < 4; ++j2) {
      int cc = w * 8 + j2 * 2;
      float v0 = xb[(size_t)(c0 + cc) * 256 + l];
      float v1x = xb[(size_t)(c0 + cc + 1) * 256 + l];
      int cb = (cc * 2) ^ ((l & 7) << 4);
      *(u32*)(sm.s.Bt + l * 128 + cb) = pk2(v0, v1x);
    }
    __syncthreads();
    #pragma unroll
    for (int ks = 0; ks < 2; ++ks) {
      int k0 = ks * 32;
      bf8 a0 = ldsFrag(sm.s.A, rows0,      k0, 128);
      bf8 a1 = ldsFrag(sm.s.A, rows0 + 16, k0, 128);
      bf8 b0 = ldsFrag(sm.s.Bt, cols0,      k0, 128);
      bf8 b1 = ldsFrag(sm.s.Bt, cols0 + 16, k0, 128);
      acc[0][0] = MFMA(a0, b0, acc[0][0]);
      acc[0][1] = MFMA(a0, b1, acc[0][1]);
      acc[1][0] = MFMA(a1, b0, acc[1][0]);
      acc[1][1] = MFMA(a1, b1, acc[1][1]);
    }
    __syncthreads();
  }
  #pragma unroll
  for (int i = 0; i < 2; ++i)
    #pragma unroll
    for (int r = 0; r < 4; ++r) {
      int d = rows0 + i * 16 + lr + r;
      float s1 = g1[d] * rsqrtf(v1[d] + 1e-5f);
      float t1 = (bdr[d] - m1[d]) * s1 + be1[d];
      #pragma unroll
      for (int j = 0; j < 2; ++j) {
        int hwl = cols0 + j * 16 + lc;
        sm.e.y[d * 65 + hwl] = fmaxf(acc[i][j][r] * s1 + t1, 0.f);
      }
    }
  __syncthreads();
  { int part = t >> 6, col = t & 63;
    float s = 0.f;
    #pragma unroll
    for (int i2 = 0; i2 < 16; ++i2) s += sm.e.y[(part * 16 + i2) * 65 + col];
    sm.e.musum[part * 64 + col] = s;
  }
  __syncthreads();
  if (t < 64) {
    float m = 0.f;
    #pragma unroll
    for (int p = 0; p < 8; ++p) m += sm.e.musum[p * 64 + t];
    sm.e.mu[t] = m * (1.0f / 128.0f);
  }
  __syncthreads();
  const float ISM = 0.08838834764831845f;   // 1/sqrt(128)
  { int hwl = t >> 3, dc = (t & 7) * 16;
    float muv = sm.e.mu[hwl];
    u32 q[8];
    #pragma unroll
    for (int jj = 0; jj < 8; ++jj) {
      float a = (sm.e.y[(dc + 2 * jj)     * 65 + hwl] - muv) * ISM;
      float c = (sm.e.y[(dc + 2 * jj + 1) * 65 + hwl] - muv) * ISM;
      q[jj] = pk2(a, c);
    }
    uint4* d4 = (uint4*)(Wg + ((size_t)(b * 256 + hw0 + hwl) * 128 + dc));
    d4[0] = make_uint4(q[0], q[1], q[2], q[3]);
    d4[1] = make_uint4(q[4], q[5], q[6], q[7]);
  }
  { int d = t >> 2, hc = (t & 3) * 16;
    u32 q[8];
    #pragma unroll
    for (int jj = 0; jj < 8; ++jj) {
      int h0 = hc + 2 * jj, h1 = hc + 2 * jj + 1;
      float a = (sm.e.y[d * 65 + h0] - sm.e.mu[h0]) * ISM;
      float c = (sm.e.y[d * 65 + h1] - sm.e.mu[h1]) * ISM;
      q[jj] = pk2(a, c);
    }
    uint4* d4 = (uint4*)(WTg + ((size_t)(b * 128 + d) * 256 + hw0 + hc));
    d4[0] = make_uint4(q[0], q[1], q[2], q[3]);
    d4[1] = make_uint4(q[4], q[5], q[6], q[7]);
  }
}

// =====================================================================
// K3: per-batch Gram + Newton-Schulz, restructured: 3 passes/iter, 3 barriers/iter,
//     G B-frags register-resident, 32x32x16 MFMA, 64x64 tiles, b64 epilogues.
// 64 WGs x 512 threads; dyn LDS = 5 x 32KB slots = 160KB
// slots: [0]=Y [1]=Z [2]=t1(P') [3]=t2(T) [4]=t3(P2)/G ; WT staging overlays t1+t2
// =====================================================================
extern __shared__ char smns[];
__global__ __launch_bounds__(512, 2) void k_ns(const u16* __restrict__ WT,
                                               u16* __restrict__ yf, float* __restrict__ normAg){
  int b = blockIdx.x, t = threadIdx.x;
  char* Yb = smns;
  char* Zb = smns + 32768;
  char* T1 = smns + 65536;
  char* T2 = smns + 98304;
  char* T3 = smns + 131072;           // also G, also temp WT-staging uses T1+T2
  char* WTl = smns + 65536;           // [128][512B] swz
  char* G   = T3;
  float* trp = (float*)smns;          // overlays Y[0] during Gram

  int w = t >> 6, l = t & 63;
  int wq = w & 3;
  int R0 = (wq >> 1) * 64, C0 = (wq & 1) * 64;   // iter-phase tile (same for w and w+4)

  { // stage WT[b] -> WTl swizzled
    const u16* src = WT + (size_t)b * 32768;
    int row = t >> 2, q = t & 3;
    #pragma unroll
    for (int j = 0; j < 8; ++j) {
      int c16 = q + j * 4;
      bf8 v = *(const bf8*)(src + row * 256 + c16 * 8);
      int ph = c16 ^ (row & 15);
      *(bf8*)(WTl + row * 512 + ph * 16) = v;
    }
  }
  if (t == 0) *trp = 0.f;
  __syncthreads();

  // ---- Gram: Gw = WT @ WT^T (128x128, K=256); 8 waves x (32x64 tiles) ----
  int R0g = (w & 3) * 32, C0g = (w >> 2) * 64;
  const f16f fz16 = {};
  f16f gac[2]; gac[0] = fz16; gac[1] = fz16;
  #pragma unroll
  for (int ks = 0; ks < 16; ++ks){
    bf8 a  = fragWT(WTl, R0g,      ks, l);
    bf8 b0 = fragWT(WTl, C0g,      ks, l);
    bf8 b1 = fragWT(WTl, C0g + 32, ks, l);
    gac[0] = MFMA32(a, b0, gac[0]);
    gac[1] = MFMA32(a, b1, gac[1]);
  }
  // trace
  float tp = 0.f;
  #pragma unroll
  for (int ci = 0; ci < 2; ++ci)
    #pragma unroll
    for (int e = 0; e < 16; ++e){
      int row = R0g + (e & 3) + 8 * (e >> 2) + ((l >> 5) << 2);
      int col = C0g + ci * 32 + (l & 31);
      if (row == col) tp += gac[ci][e];
    }
  #pragma unroll
  for (int off = 32; off > 0; off >>= 1) tp += __shfl_down(tp, off);
  if (l == 0) atomicAdd(trp, tp);
  __syncthreads();

  float normA = fmaxf(*trp / 3.0f, 1e-12f);
  if (t == 0) normAg[b] = normA;
  float inv = 1.0f / normA;
  // write G = Gw*inv (transposed store, b64)
  #pragma unroll
  for (int ci = 0; ci < 2; ++ci)
    #pragma unroll
    for (int g = 0; g < 4; ++g){
      int srow = C0g + ci * 32 + (l & 31);
      int scol = R0g + g * 8 + ((l >> 5) << 2);
      float v0 = gac[ci][g * 4 + 0] * inv, v1 = gac[ci][g * 4 + 1] * inv;
      float v2 = gac[ci][g * 4 + 2] * inv, v3 = gac[ci][g * 4 + 3] * inv;
      *(uint2*)nsAddr(G, srow, scol) = make_uint2(pk2(v0, v1), pk2(v2, v3));
    }
  __syncthreads();

  // ---- load G B-frags to regs; init Y = 1.5I - 0.5G, Z = -0.5I ----
  bf8 gA[8], gB[8];
  #pragma unroll
  for (int ks = 0; ks < 8; ++ks){
    gA[ks] = fragNS(G, C0,      ks, l);
    gB[ks] = fragNS(G, C0 + 32, ks, l);
  }
  { int row = t >> 2, q4 = t & 3;
    #pragma unroll
    for (int j = 0; j < 4; ++j){
      int c16 = q4 * 4 + j;
      int ph = c16 ^ (row & 15);
      bf8 gg = *(const bf8*)(G + row * 256 + ph * 16);
      bf8 yv, zv;
      #pragma unroll
      for (int e = 0; e < 8; ++e){
        int col = c16 * 8 + e;
        float y = -0.5f * bf2f((u16)gg[e]) + ((col == row) ? 1.5f : 0.f);
        yv[e] = (short)f2bf(y);
        zv[e] = (col == row) ? (short)f2bf(-0.5f) : (short)0;
      }
      *(bf8*)(Yb + row * 256 + ph * 16) = yv;
      *(bf8*)(Zb + row * 256 + ph * 16) = zv;
    }
  }
  __syncthreads();

  // ---- NS iterations ----
  float z0 = 1.5f;
  for (int it = 0; it < 4; ++it){
    // pass1: w0-3: t1 = Z@G + z0*I ; w4-7: t3 = Y@G
    {
      f16f acc[2][2]; acc[0][0] = fz16; acc[0][1] = fz16; acc[1][0] = fz16; acc[1][1] = fz16;
      const char* As = (w < 4) ? Zb : Yb;
      #pragma unroll
      for (int ks = 0; ks < 8; ++ks){
        bf8 a0 = fragNS(As, R0,      ks, l);
        bf8 a1 = fragNS(As, R0 + 32, ks, l);
        acc[0][0] = MFMA32(a0, gA[ks], acc[0][0]); acc[0][1] = MFMA32(a0, gB[ks], acc[0][1]);
        acc[1][0] = MFMA32(a1, gA[ks], acc[1][0]); acc[1][1] = MFMA32(a1, gB[ks], acc[1][1]);
      }
      writeTile((w < 4) ? T1 : T3, acc, R0, C0, l, 1.0f, (w < 4) ? z0 : 0.f, nullptr);
    }
    __syncthreads();

    // pass2: w0-3: t2 = -0.5 * t1 @ Y ; all: pre-read additive frags for pass3
    uint2 adv[16];
    {
      const char* addsrc = (w < 4) ? Zb : Yb;
      #pragma unroll
      for (int ri = 0; ri < 2; ++ri)
      #pragma unroll
      for (int ci = 0; ci < 2; ++ci)
      #pragma unroll
      for (int g = 0; g < 4; ++g){
        int srow = C0 + ci * 32 + (l & 31);
        int scol = R0 + ri * 32 + g * 8 + ((l >> 5) << 2);
        adv[(ri * 2 + ci) * 4 + g] = *(const uint2*)nsAddr((char*)addsrc, srow, scol);
      }
      if (w < 4){
        f16f acc[2][2]; acc[0][0] = fz16; acc[0][1] = fz16; acc[1][0] = fz16; acc[1][1] = fz16;
        mmPass(T1, Yb, acc, R0, C0, l);
        writeTile(T2, acc, R0, C0, l, -0.5f, 0.f, nullptr);
      }
    }
    __syncthreads();

    // pass3: w0-3: Z = t2@t1 + 1.5Z (skip on last iter); w4-7: Y = t3@t2 + 1.5Y
    if ((w >= 4) || (it < 3)){
      f16f acc[2][2]; acc[0][0] = fz16; acc[0][1] = fz16; acc[1][0] = fz16; acc[1][1] = fz16;
      const char* A3 = (w < 4) ? T2 : T3;
      const char* B3 = (w < 4) ? T1 : T2;
      mmPass(A3, B3, acc, R0, C0, l);
      writeTile((w < 4) ? Zb : Yb, acc, R0, C0, l, 1.0f, 0.f, adv);
    }
    __syncthreads();
    z0 *= 1.5f;
  }

  { // write yf[b] (unswizzled row-major)
    int row = t >> 2, q = t & 3;
    u16* dst = yf + (size_t)b * 16384 + row * 128;
    #pragma unroll
    for (int j = 0; j < 4; ++j) {
      int c16 = q * 4 + j;
      int ph = c16 ^ (row & 15);
      *(bf8*)(dst + c16 * 8) = *(const bf8*)(Yb + row * 256 + ph * 16);
    }
  }
}

// =====================================================================
// K4: S = W @ yf @ W^T / sqrt(normA), then BN2 row-affine + rc -> s_post bf16
// =====================================================================
extern __shared__ char smex[];
__global__ __launch_bounds__(512) void k_expand(
    const u16* __restrict__ Wg, const u16* __restrict__ yf, const float* __restrict__ normAg,
    const float* __restrict__ g2, const float* __restrict__ be2, const float* __restrict__ m2,
    const float* __restrict__ v2, const float* __restrict__ rcw, const float* __restrict__ rcb,
    u16* __restrict__ sp){
  int blk = blockIdx.x, b = blk >> 2, iband = blk & 3;
  char* Bm = smex;
  char* Yl = smex + 65536;
  char* El = smex + 98304;
  int t = threadIdx.x;
  { const u16* src = Wg + (size_t)b * 32768;
    int row = t >> 1, q = t & 1;
    #pragma unroll
    for (int j = 0; j < 8; ++j) {
      int c16 = q + j * 2;
      bf8 v = *(const bf8*)(src + row * 128 + c16 * 8);
      int ph = c16 ^ (row & 7);
      *(bf8*)(Bm + row * 256 + ph * 16) = v;
    } }
  { const u16* src = yf + (size_t)b * 16384;
    int row = t >> 2, q = t & 3;
    #pragma unroll
    for (int j = 0; j < 4; ++j) {
      int c16 = q + j * 4;
      bf8 v = *(const bf8*)(src + row * 128 + c16 * 8);
      int ph = c16 ^ (row & 7);
      *(bf8*)(Yl + row * 256 + ph * 16) = v;
    } }
  __syncthreads();
  int w = t >> 6, l = t & 63, lc = l & 15, lr = (l >> 4) * 4;
  const f4 fz = {0.f, 0.f, 0.f, 0.f};
  { int r0 = (w >> 2) * 32, c0 = (w & 3) * 32;
    f4 acc[2][2];
    acc[0][0] = fz; acc[0][1] = fz; acc[1][0] = fz; acc[1][1] = fz;
    #pragma unroll
    for (int kk = 0; kk < 4; ++kk) {
      int k0 = kk * 32;
      bf8 a0 = ldsFrag(Bm, iband * 64 + r0,      k0, 256);
      bf8 a1 = ldsFrag(Bm, iband * 64 + r0 + 16, k0, 256);
      bf8 b0 = ldsFrag(Yl, c0,      k0, 256);
      bf8 b1 = ldsFrag(Yl, c0 + 16, k0, 256);
      acc[0][0] = MFMA(a0, b0, acc[0][0]); acc[0][1] = MFMA(a0, b1, acc[0][1]);
      acc[1][0] = MFMA(a1, b0, acc[1][0]); acc[1][1] = MFMA(a1, b1, acc[1][1]);
    }
    #pragma unroll
    for (int i = 0; i < 2; ++i)
      #pragma unroll
      for (int j = 0; j < 2; ++j)
        #pragma unroll
        for (int r = 0; r < 4; ++r)
          ldsPut(El, r0 + i * 16 + lr + r, c0 + j * 16 + lc, 256, f2bf(acc[i][j][r]));
  }
  __syncthreads();
  { float invs = rsqrtf(normAg[b]);
    int r0 = (w >> 2) * 32, c0 = (w & 3) * 64;
    f4 acc[2][4];
    #pragma unroll
    for (int i = 0; i < 2; ++i)
      #pragma unroll
      for (int j = 0; j < 4; ++j) acc[i][j] = fz;
    #pragma unroll
    for (int kk = 0; kk < 4; ++kk) {
      int k0 = kk * 32;
      bf8 a0 = ldsFrag(El, r0,      k0, 256);
      bf8 a1 = ldsFrag(El, r0 + 16, k0, 256);
      bf8 b0 = ldsFrag(Bm, c0,      k0, 256);
      bf8 b1 = ldsFrag(Bm, c0 + 16, k0, 256);
      bf8 b2 = ldsFrag(Bm, c0 + 32, k0, 256);
      bf8 b3 = ldsFrag(Bm, c0 + 48, k0, 256);
      acc[0][0] = MFMA(a0, b0, acc[0][0]); acc[0][1] = MFMA(a0, b1, acc[0][1]);
      acc[0][2] = MFMA(a0, b2, acc[0][2]); acc[0][3] = MFMA(a0, b3, acc[0][3]);
      acc[1][0] = MFMA(a1, b0, acc[1][0]); acc[1][1] = MFMA(a1, b1, acc[1][1]);
      acc[1][2] = MFMA(a1, b2, acc[1][2]); acc[1][3] = MFMA(a1, b3, acc[1][3]);
    }
    #pragma unroll
    for (int i = 0; i < 2; ++i)
      #pragma unroll
      for (int r = 0; r < 4; ++r) {
        int il = r0 + i * 16 + lr + r;
        int ig = iband * 64 + il;
        float bs = g2[ig] * rsqrtf(v2[ig] + 1e-5f);
        float al = bs * rcw[ig];
        float be = (be2[ig] - m2[ig] * bs) * rcw[ig] + rcb[ig];
        #pragma unroll
        for (int j = 0; j < 4; ++j) {
          int jg = c0 + j * 16 + lc;
          sp[(size_t)b * 65536 + ig * 256 + jg] = f2bf(acc[i][j][r] * invs * al + be);
        }
      }
  }
}

// =====================================================================
// K5: logits[b][r] += s_post[b][:] . fc_w[r][:]
// =====================================================================
extern __shared__ char smfc[];
__global__ __launch_bounds__(512) void k_fc(const u16* __restrict__ sp,
                                            const float* __restrict__ fcw,
                                            float* __restrict__ logits){
  int kc = blockIdx.x >> 1, rh = blockIdx.x & 1;
  int k0 = kc * 256, rbase = rh * 128;
  char* Al = smfc;
  char* Bl = smfc + 32768;
  int t = threadIdx.x;
  { int row = t >> 3, q = t & 7;
    #pragma unroll
    for (int j = 0; j < 4; ++j) {
      int c16 = q + j * 8;
      bf8 v = *(const bf8*)(sp + (size_t)row * 65536 + k0 + c16 * 8);
      int ph = c16 ^ (row & 7);
      *(bf8*)(Al + row * 512 + ph * 16) = v;
    } }
  { int lane16 = t & 15;
    #pragma unroll
    for (int pass = 0; pass < 4; ++pass) {
      int row = (t >> 4) + pass * 32;
      #pragma unroll
      for (int j = 0; j < 4; ++j) {
        int k = lane16 * 4 + j * 64;
        float4 v = *(const float4*)(fcw + (size_t)(rbase + row) * 65536 + k0 + k);
        int off = (k * 2) ^ ((row & 7) << 4);
        *(u32*)(Bl + row * 512 + off)     = pk2(v.x, v.y);
        *(u32*)(Bl + row * 512 + off + 4) = pk2(v.z, v.w);
      }
    } }
  __syncthreads();
  int w = t >> 6, l = t & 63, lc = l & 15, lr = (l >> 4) * 4;
  int r0 = (w >> 2) * 32, c0 = (w & 3) * 32;
  const f4 fz = {0.f, 0.f, 0.f, 0.f};
  f4 acc[2][2];
  acc[0][0] = fz; acc[0][1] = fz; acc[1][0] = fz; acc[1][1] = fz;
  #pragma unroll
  for (int kk = 0; kk < 8; ++kk) {
    int ks = kk * 32;
    bf8 a0 = ldsFrag(Al, r0,      ks, 512);
    bf8 a1 = ldsFrag(Al, r0 + 16, ks, 512);
    bf8 b0 = ldsFrag(Bl, c0,      ks, 512);
    bf8 b1 = ldsFrag(Bl, c0 + 16, ks, 512);
    acc[0][0] = MFMA(a0, b0, acc[0][0]); acc[0][1] = MFMA(a0, b1, acc[0][1]);
    acc[1][0] = MFMA(a1, b0, acc[1][0]); acc[1][1] = MFMA(a1, b1, acc[1][1]);
  }
  #pragma unroll
  for (int i = 0; i < 2; ++i)
    #pragma unroll
    for (int j = 0; j < 2; ++j)
      #pragma unroll
      for (int r = 0; r < 4; ++r) {
        int row = r0 + i * 16 + lr + r;
        int col = rbase + c0 + j * 16 + lc;
        atomicAdd(logits + row * 256 + col, acc[i][j][r]);
      }
}

// =====================================================================
// K7: out = x * sigmoid(logits + fc_b)
// =====================================================================
__global__ __launch_bounds__(256) void k_mul(const float* __restrict__ x,
                                             const float* __restrict__ logits,
                                             const float* __restrict__ fcb,
                                             float* __restrict__ out, int n4){
  int i = blockIdx.x * 256 + threadIdx.x;
  int str = gridDim.x * 256;
  for (; i < n4; i += str) {
    int e = i << 2;
    int b = e >> 18;
    int hw = e & 255;
    float4 xv = ((const float4*)x)[i];
    float4 lg = *(const float4*)(logits + (b << 8) + hw);
    float4 fb = *(const float4*)(fcb + hw);
    float4 o;
    o.x = xv.x / (1.f + expf(-(lg.x + fb.x)));
    o.y = xv.y / (1.f + expf(-(lg.y + fb.y)));
    o.z = xv.z / (1.f + expf(-(lg.z + fb.z)));
    o.w = xv.w / (1.f + expf(-(lg.w + fb.w)));
    ((float4*)out)[i] = o;
  }
}

// =====================================================================
extern "C" void kernel_launch(void* const* d_in, const int* in_sizes, int n_in,
                              void* d_out, int out_size, void* d_ws, size_t ws_size,
                              hipStream_t stream){
  const float* x   = (const float*)d_in[0];
  const float* wdr = (const float*)d_in[1];
  const float* bdr = (const float*)d_in[2];
  const float* g1  = (const float*)d_in[3];
  const float* be1 = (const float*)d_in[4];
  const float* m1  = (const float*)d_in[5];
  const float* v1  = (const float*)d_in[6];
  const float* g2  = (const float*)d_in[7];
  const float* be2 = (const float*)d_in[8];
  const float* m2  = (const float*)d_in[9];
  const float* v2  = (const float*)d_in[10];
  const float* rcw = (const float*)d_in[11];
  const float* rcb = (const float*)d_in[12];
  const float* fcw = (const float*)d_in[13];
  const float* fcb = (const float*)d_in[14];
  float* out = (float*)d_out;
  char* ws = (char*)d_ws;
  u16*   Wg  = (u16*)(ws);
  u16*   WTg = (u16*)(ws + (4u  << 20));
  u16*   yfg = (u16*)(ws + (8u  << 20));
  float* nAg = (float*)(ws + (10u << 20));
  u16*   spg = (u16*)(ws + (11u << 20));
  float* lgt = (float*)(ws + (20u << 20));

  hipFuncSetAttribute((const void*)k_ns,     hipFuncAttributeMaxDynamicSharedMemorySize, 163840);
  hipFuncSetAttribute((const void*)k_expand, hipFuncAttributeMaxDynamicSharedMemorySize, 114688);
  hipFuncSetAttribute((const void*)k_fc,     hipFuncAttributeMaxDynamicSharedMemorySize, 98304);

  k_zero  <<<64,   256, 0,      stream>>>(lgt);
  k_conv  <<<256,  512, 0,      stream>>>(x, wdr, bdr, g1, be1, m1, v1, Wg, WTg);
  k_ns    <<<64,   512, 163840, stream>>>(WTg, yfg, nAg);
  k_expand<<<256,  512, 114688, stream>>>(Wg, yfg, nAg, g2, be2, m2, v2, rcw, rcb, spg);
  k_fc    <<<512,  512, 98304,  stream>>>(spg, fcw, lgt);
  k_mul   <<<2048, 256, 0,      stream>>>(x, lgt, fcb, out, 4194304);
}

// Round 3
// 115.652 us; speedup vs baseline: 1.2640x; 1.0556x over previous
//
#include <hip/hip_runtime.h>

typedef unsigned short u16;
typedef unsigned int   u32;
typedef __attribute__((ext_vector_type(8))) short bf8;   // 8 x bf16 (4 VGPRs)
typedef __attribute__((ext_vector_type(4))) float f4;    // 4 x f32 accumulator
typedef __attribute__((ext_vector_type(16))) float f16f; // 16 x f32 accumulator (32x32 MFMA)

#define MFMA(a,b,c)   __builtin_amdgcn_mfma_f32_16x16x32_bf16(a,b,c,0,0,0)
#define MFMA32(a,b,c) __builtin_amdgcn_mfma_f32_32x32x16_bf16(a,b,c,0,0,0)

__device__ __forceinline__ u16 f2bf(float f){
  u32 u = __float_as_uint(f);
  u += 0x7fffu + ((u >> 16) & 1u);          // RNE
  return (u16)(u >> 16);
}
__device__ __forceinline__ float bf2f(u16 h){ return __uint_as_float(((u32)h) << 16); }
__device__ __forceinline__ u32 pk2(float a, float b){ return (u32)f2bf(a) | ((u32)f2bf(b) << 16); }

// ---- swizzled LDS bf16 matrix helpers (16x16 path) ----
__device__ __forceinline__ bf8 ldsFrag(const char* m, int row0, int k0, int pitch){
  int l = threadIdx.x & 63;
  int r = row0 + (l & 15);
  int kb = ((k0 + ((l >> 4) << 3)) << 1) ^ ((r & 7) << 4);
  return *(const bf8*)(m + r * pitch + kb);
}
__device__ __forceinline__ void ldsPut(char* m, int row, int col, int pitch, u16 v){
  int kb = (col << 1) ^ ((row & 7) << 4);
  *(u16*)(m + row * pitch + kb) = v;
}

// ---- k_ns helpers: pitch-256B rows, chunk swizzle (row&15)<<4 ----
__device__ __forceinline__ bf8 fragNS(const char* m, int r0, int ks, int l){
  int r = r0 + (l & 31);
  int kb = ((ks << 5) + ((l >> 5) << 4)) ^ ((r & 15) << 4);
  return *(const bf8*)(m + r * 256 + kb);
}
__device__ __forceinline__ bf8 fragWT(const char* m, int r0, int ks, int l){
  int r = r0 + (l & 31);
  int kb = ((ks << 5) + ((l >> 5) << 4)) ^ ((r & 15) << 4);
  return *(const bf8*)(m + r * 512 + kb);
}
__device__ __forceinline__ char* nsAddr(char* m, int row, int col4){
  return m + row * 256 + ((col4 << 1) ^ ((row & 15) << 4));
}

// 64x64 matmul pass: acc += A[R0.., :] @ Bsym[C0.., :]^T
__device__ __forceinline__ void mmPass(const char* A, const char* B, f16f (&acc)[2][2],
                                       int R0, int C0, int l){
  #pragma unroll
  for (int ks = 0; ks < 8; ++ks){
    bf8 a0 = fragNS(A, R0,      ks, l);
    bf8 a1 = fragNS(A, R0 + 32, ks, l);
    bf8 b0 = fragNS(B, C0,      ks, l);
    bf8 b1 = fragNS(B, C0 + 32, ks, l);
    acc[0][0] = MFMA32(a0, b0, acc[0][0]); acc[0][1] = MFMA32(a0, b1, acc[0][1]);
    acc[1][0] = MFMA32(a1, b0, acc[1][0]); acc[1][1] = MFMA32(a1, b1, acc[1][1]);
  }
}

// write 64x64 tile transposed (valid by symmetry), vectorized b64 stores.
__device__ __forceinline__ void writeTile(char* D, const f16f (&acc)[2][2], int R0, int C0, int l,
                                          float scale, float dval, const uint2* adv){
  #pragma unroll
  for (int ri = 0; ri < 2; ++ri)
  #pragma unroll
  for (int ci = 0; ci < 2; ++ci)
  #pragma unroll
  for (int g = 0; g < 4; ++g){
    int srow = C0 + ci * 32 + (l & 31);
    int scol = R0 + ri * 32 + g * 8 + ((l >> 5) << 2);
    float v[4];
    #pragma unroll
    for (int q = 0; q < 4; ++q){
      float x = scale * acc[ri][ci][g * 4 + q];
      x += ((scol + q) == srow) ? dval : 0.f;
      v[q] = x;
    }
    if (adv){
      uint2 ad = adv[(ri * 2 + ci) * 4 + g];
      v[0] += 1.5f * bf2f((u16)ad.x);
      v[1] += 1.5f * bf2f((u16)(ad.x >> 16));
      v[2] += 1.5f * bf2f((u16)ad.y);
      v[3] += 1.5f * bf2f((u16)(ad.y >> 16));
    }
    *(uint2*)nsAddr(D, srow, scol) = make_uint2(pk2(v[0], v[1]), pk2(v[2], v[3]));
  }
}

// =====================================================================
// K_prep: zero logits + convert w_dr -> bf16 pre-swizzled per-chunk LDS image
// prep[e]: e = chunk*8192 + d*64 + cb2, value = bf16(wdr[d][chunk*64 + c]),
//          c = ((cb2*2) ^ ((d&7)<<4)) >> 1
// =====================================================================
__global__ __launch_bounds__(256) void k_prep(const float* __restrict__ wdr,
                                              float* __restrict__ logits,
                                              u16* __restrict__ prep){
  int i = blockIdx.x * 256 + threadIdx.x;   // grid 256 -> 65536 threads
  if (i < 16384) logits[i] = 0.f;
  #pragma unroll
  for (int j = 0; j < 2; ++j){
    int e = i + j * 65536;
    int chunk = e >> 13, rem = e & 8191, d = rem >> 6, cb2 = rem & 63;
    int c = ((cb2 * 2) ^ ((d & 7) << 4)) >> 1;
    prep[e] = f2bf(wdr[d * 1024 + chunk * 64 + c]);
  }
}

// =====================================================================
// K1: 1x1 conv GEMM + BN1 + ReLU, center over d, scale 1/sqrt(128),
//     write W [b][hw][d] and WT [b][d][hw] (bf16)
// grid 512 = 64 b x 8 hw-blocks of 32; 512 threads (8 waves);
// double-buffered LDS, async-split staging (issue-early / write-late)
// =====================================================================
__global__ __launch_bounds__(512) void k_conv(
    const u16* __restrict__ wprep, const float* __restrict__ x, const float* __restrict__ bdr,
    const float* __restrict__ g1, const float* __restrict__ be1,
    const float* __restrict__ m1, const float* __restrict__ v1,
    u16* __restrict__ Wg, u16* __restrict__ WTg){
  __shared__ union {
    struct { u16 A[2][8192]; u16 Bt[2][2048]; } s;   // A: [128][64] bf16 swz pitch128 (x2); Bt: [32][64] (x2)
    struct { float y[128 * 33]; float musum[512]; float mu[32]; } e;
  } sm;
  int t = threadIdx.x;
  int b = blockIdx.x >> 3, hw0 = (blockIdx.x & 7) * 32;
  const float* xb = x + (size_t)b * 262144 + hw0;

  int w = t >> 6, l = t & 63;
  int d0 = (w >> 1) * 32, hh = (w & 1) * 16;
  int lc = l & 15, lr = (l >> 4) * 4;

  const f4 fz = {0.f, 0.f, 0.f, 0.f};
  f4 acc[2]; acc[0] = fz; acc[1] = fz;

  int cp = t >> 5, hwl = t & 31;

  uint4 ar0, ar1;
  float br0, br1, br2, br3;
  // prologue: chunk 0 loads
  { const uint4* s4 = (const uint4*)wprep;
    ar0 = s4[t]; ar1 = s4[t + 512];
    br0 = xb[(size_t)(2 * cp)      * 256 + hwl];
    br1 = xb[(size_t)(2 * cp + 1)  * 256 + hwl];
    br2 = xb[(size_t)(2 * cp + 32) * 256 + hwl];
    br3 = xb[(size_t)(2 * cp + 33) * 256 + hwl];
  }

  for (int k = 0; k < 16; ++k){
    int cur = k & 1;
    // write staged regs -> LDS
    *(uint4*)(sm.s.A[cur] + t * 8)        = ar0;
    *(uint4*)(sm.s.A[cur] + 4096 + t * 8) = ar1;
    { int b0 = (4 * cp) ^ ((hwl & 7) << 4);
      int b1 = (4 * cp + 64) ^ ((hwl & 7) << 4);
      *(u32*)((char*)sm.s.Bt[cur] + hwl * 128 + b0) = pk2(br0, br1);
      *(u32*)((char*)sm.s.Bt[cur] + hwl * 128 + b1) = pk2(br2, br3);
    }
    __syncthreads();
    if (k < 15){
      const uint4* s4 = (const uint4*)(wprep + (k + 1) * 8192);
      ar0 = s4[t]; ar1 = s4[t + 512];
      int c0 = (k + 1) * 64;
      br0 = xb[(size_t)(c0 + 2 * cp)      * 256 + hwl];
      br1 = xb[(size_t)(c0 + 2 * cp + 1)  * 256 + hwl];
      br2 = xb[(size_t)(c0 + 2 * cp + 32) * 256 + hwl];
      br3 = xb[(size_t)(c0 + 2 * cp + 33) * 256 + hwl];
    }
    #pragma unroll
    for (int ks = 0; ks < 2; ++ks){
      int k0 = ks * 32;
      bf8 a0 = ldsFrag((const char*)sm.s.A[cur], d0,      k0, 128);
      bf8 a1 = ldsFrag((const char*)sm.s.A[cur], d0 + 16, k0, 128);
      bf8 b0 = ldsFrag((const char*)sm.s.Bt[cur], hh, k0, 128);
      acc[0] = MFMA(a0, b0, acc[0]);
      acc[1] = MFMA(a1, b0, acc[1]);
    }
    __syncthreads();
  }

  // epilogue: BN1 + ReLU -> y stage (f32, pitch 33)
  #pragma unroll
  for (int i = 0; i < 2; ++i)
    #pragma unroll
    for (int r = 0; r < 4; ++r){
      int d = d0 + i * 16 + lr + r;
      float s1 = g1[d] * rsqrtf(v1[d] + 1e-5f);
      float t1 = (bdr[d] - m1[d]) * s1 + be1[d];
      int hwp = hh + lc;
      sm.e.y[d * 33 + hwp] = fmaxf(acc[i][r] * s1 + t1, 0.f);
    }
  __syncthreads();
  { // column means over d
    int part = t >> 5, col = t & 31;
    float s = 0.f;
    #pragma unroll
    for (int i2 = 0; i2 < 8; ++i2) s += sm.e.y[(part * 8 + i2) * 33 + col];
    sm.e.musum[part * 32 + col] = s;
  }
  __syncthreads();
  if (t < 32){
    float m = 0.f;
    #pragma unroll
    for (int p = 0; p < 16; ++p) m += sm.e.musum[p * 32 + t];
    sm.e.mu[t] = m * (1.0f / 128.0f);
  }
  __syncthreads();
  const float ISM = 0.08838834764831845f;   // 1/sqrt(128)
  { // W [b][hw][d]
    int hwp = t >> 4, dc = (t & 15) * 8;
    float muv = sm.e.mu[hwp];
    u32 q[4];
    #pragma unroll
    for (int jj = 0; jj < 4; ++jj){
      float a = (sm.e.y[(dc + 2 * jj)     * 33 + hwp] - muv) * ISM;
      float c = (sm.e.y[(dc + 2 * jj + 1) * 33 + hwp] - muv) * ISM;
      q[jj] = pk2(a, c);
    }
    *(uint4*)(Wg + ((size_t)(b * 256 + hw0 + hwp) * 128 + dc)) = make_uint4(q[0], q[1], q[2], q[3]);
  }
  { // WT [b][d][hw]
    int d = t >> 2, hc = (t & 3) * 8;
    u32 q[4];
    #pragma unroll
    for (int jj = 0; jj < 4; ++jj){
      int h0 = hc + 2 * jj, h1 = hc + 2 * jj + 1;
      float a = (sm.e.y[d * 33 + h0] - sm.e.mu[h0]) * ISM;
      float c = (sm.e.y[d * 33 + h1] - sm.e.mu[h1]) * ISM;
      q[jj] = pk2(a, c);
    }
    *(uint4*)(WTg + ((size_t)(b * 128 + d) * 256 + hw0 + hc)) = make_uint4(q[0], q[1], q[2], q[3]);
  }
}

// =====================================================================
// K3: per-batch Gram + Newton-Schulz (3 passes/iter, G register-resident,
//     32x32x16 MFMA, 64x64 tiles, b64 epilogues)
// =====================================================================
extern __shared__ char smns[];
__global__ __launch_bounds__(512, 2) void k_ns(const u16* __restrict__ WT,
                                               u16* __restrict__ yf, float* __restrict__ normAg){
  int b = blockIdx.x, t = threadIdx.x;
  char* Yb = smns;
  char* Zb = smns + 32768;
  char* T1 = smns + 65536;
  char* T2 = smns + 98304;
  char* T3 = smns + 131072;
  char* WTl = smns + 65536;
  char* G   = T3;
  float* trp = (float*)smns;

  int w = t >> 6, l = t & 63;
  int wq = w & 3;
  int R0 = (wq >> 1) * 64, C0 = (wq & 1) * 64;

  { const u16* src = WT + (size_t)b * 32768;
    int row = t >> 2, q = t & 3;
    #pragma unroll
    for (int j = 0; j < 8; ++j) {
      int c16 = q + j * 4;
      bf8 v = *(const bf8*)(src + row * 256 + c16 * 8);
      int ph = c16 ^ (row & 15);
      *(bf8*)(WTl + row * 512 + ph * 16) = v;
    }
  }
  if (t == 0) *trp = 0.f;
  __syncthreads();

  int R0g = (w & 3) * 32, C0g = (w >> 2) * 64;
  const f16f fz16 = {};
  f16f gac[2]; gac[0] = fz16; gac[1] = fz16;
  #pragma unroll
  for (int ks = 0; ks < 16; ++ks){
    bf8 a  = fragWT(WTl, R0g,      ks, l);
    bf8 b0 = fragWT(WTl, C0g,      ks, l);
    bf8 b1 = fragWT(WTl, C0g + 32, ks, l);
    gac[0] = MFMA32(a, b0, gac[0]);
    gac[1] = MFMA32(a, b1, gac[1]);
  }
  float tp = 0.f;
  #pragma unroll
  for (int ci = 0; ci < 2; ++ci)
    #pragma unroll
    for (int e = 0; e < 16; ++e){
      int row = R0g + (e & 3) + 8 * (e >> 2) + ((l >> 5) << 2);
      int col = C0g + ci * 32 + (l & 31);
      if (row == col) tp += gac[ci][e];
    }
  #pragma unroll
  for (int off = 32; off > 0; off >>= 1) tp += __shfl_down(tp, off);
  if (l == 0) atomicAdd(trp, tp);
  __syncthreads();

  float normA = fmaxf(*trp / 3.0f, 1e-12f);
  if (t == 0) normAg[b] = normA;
  float inv = 1.0f / normA;
  #pragma unroll
  for (int ci = 0; ci < 2; ++ci)
    #pragma unroll
    for (int g = 0; g < 4; ++g){
      int srow = C0g + ci * 32 + (l & 31);
      int scol = R0g + g * 8 + ((l >> 5) << 2);
      float v0 = gac[ci][g * 4 + 0] * inv, v1 = gac[ci][g * 4 + 1] * inv;
      float v2 = gac[ci][g * 4 + 2] * inv, v3 = gac[ci][g * 4 + 3] * inv;
      *(uint2*)nsAddr(G, srow, scol) = make_uint2(pk2(v0, v1), pk2(v2, v3));
    }
  __syncthreads();

  bf8 gA[8], gB[8];
  #pragma unroll
  for (int ks = 0; ks < 8; ++ks){
    gA[ks] = fragNS(G, C0,      ks, l);
    gB[ks] = fragNS(G, C0 + 32, ks, l);
  }
  { int row = t >> 2, q4 = t & 3;
    #pragma unroll
    for (int j = 0; j < 4; ++j){
      int c16 = q4 * 4 + j;
      int ph = c16 ^ (row & 15);
      bf8 gg = *(const bf8*)(G + row * 256 + ph * 16);
      bf8 yv, zv;
      #pragma unroll
      for (int e = 0; e < 8; ++e){
        int col = c16 * 8 + e;
        float y = -0.5f * bf2f((u16)gg[e]) + ((col == row) ? 1.5f : 0.f);
        yv[e] = (short)f2bf(y);
        zv[e] = (col == row) ? (short)f2bf(-0.5f) : (short)0;
      }
      *(bf8*)(Yb + row * 256 + ph * 16) = yv;
      *(bf8*)(Zb + row * 256 + ph * 16) = zv;
    }
  }
  __syncthreads();

  float z0 = 1.5f;
  for (int it = 0; it < 4; ++it){
    {
      f16f acc[2][2]; acc[0][0] = fz16; acc[0][1] = fz16; acc[1][0] = fz16; acc[1][1] = fz16;
      const char* As = (w < 4) ? Zb : Yb;
      #pragma unroll
      for (int ks = 0; ks < 8; ++ks){
        bf8 a0 = fragNS(As, R0,      ks, l);
        bf8 a1 = fragNS(As, R0 + 32, ks, l);
        acc[0][0] = MFMA32(a0, gA[ks], acc[0][0]); acc[0][1] = MFMA32(a0, gB[ks], acc[0][1]);
        acc[1][0] = MFMA32(a1, gA[ks], acc[1][0]); acc[1][1] = MFMA32(a1, gB[ks], acc[1][1]);
      }
      writeTile((w < 4) ? T1 : T3, acc, R0, C0, l, 1.0f, (w < 4) ? z0 : 0.f, nullptr);
    }
    __syncthreads();

    uint2 adv[16];
    {
      const char* addsrc = (w < 4) ? Zb : Yb;
      #pragma unroll
      for (int ri = 0; ri < 2; ++ri)
      #pragma unroll
      for (int ci = 0; ci < 2; ++ci)
      #pragma unroll
      for (int g = 0; g < 4; ++g){
        int srow = C0 + ci * 32 + (l & 31);
        int scol = R0 + ri * 32 + g * 8 + ((l >> 5) << 2);
        adv[(ri * 2 + ci) * 4 + g] = *(const uint2*)nsAddr((char*)addsrc, srow, scol);
      }
      if (w < 4){
        f16f acc[2][2]; acc[0][0] = fz16; acc[0][1] = fz16; acc[1][0] = fz16; acc[1][1] = fz16;
        mmPass(T1, Yb, acc, R0, C0, l);
        writeTile(T2, acc, R0, C0, l, -0.5f, 0.f, nullptr);
      }
    }
    __syncthreads();

    if ((w >= 4) || (it < 3)){
      f16f acc[2][2]; acc[0][0] = fz16; acc[0][1] = fz16; acc[1][0] = fz16; acc[1][1] = fz16;
      const char* A3 = (w < 4) ? T2 : T3;
      const char* B3 = (w < 4) ? T1 : T2;
      mmPass(A3, B3, acc, R0, C0, l);
      writeTile((w < 4) ? Zb : Yb, acc, R0, C0, l, 1.0f, 0.f, adv);
    }
    __syncthreads();
    z0 *= 1.5f;
  }

  { int row = t >> 2, q = t & 3;
    u16* dst = yf + (size_t)b * 16384 + row * 128;
    #pragma unroll
    for (int j = 0; j < 4; ++j) {
      int c16 = q * 4 + j;
      int ph = c16 ^ (row & 15);
      *(bf8*)(dst + c16 * 8) = *(const bf8*)(Yb + row * 256 + ph * 16);
    }
  }
}

// =====================================================================
// K4: S = W @ yf @ W^T / sqrt(normA), then BN2 row-affine + rc -> s_post bf16
// =====================================================================
extern __shared__ char smex[];
__global__ __launch_bounds__(512) void k_expand(
    const u16* __restrict__ Wg, const u16* __restrict__ yf, const float* __restrict__ normAg,
    const float* __restrict__ g2, const float* __restrict__ be2, const float* __restrict__ m2,
    const float* __restrict__ v2, const float* __restrict__ rcw, const float* __restrict__ rcb,
    u16* __restrict__ sp){
  int blk = blockIdx.x, b = blk >> 2, iband = blk & 3;
  char* Bm = smex;
  char* Yl = smex + 65536;
  char* El = smex + 98304;
  int t = threadIdx.x;
  { const u16* src = Wg + (size_t)b * 32768;
    int row = t >> 1, q = t & 1;
    #pragma unroll
    for (int j = 0; j < 8; ++j) {
      int c16 = q + j * 2;
      bf8 v = *(const bf8*)(src + row * 128 + c16 * 8);
      int ph = c16 ^ (row & 7);
      *(bf8*)(Bm + row * 256 + ph * 16) = v;
    } }
  { const u16* src = yf + (size_t)b * 16384;
    int row = t >> 2, q = t & 3;
    #pragma unroll
    for (int j = 0; j < 4; ++j) {
      int c16 = q + j * 4;
      bf8 v = *(const bf8*)(src + row * 128 + c16 * 8);
      int ph = c16 ^ (row & 7);
      *(bf8*)(Yl + row * 256 + ph * 16) = v;
    } }
  __syncthreads();
  int w = t >> 6, l = t & 63, lc = l & 15, lr = (l >> 4) * 4;
  const f4 fz = {0.f, 0.f, 0.f, 0.f};
  { int r0 = (w >> 2) * 32, c0 = (w & 3) * 32;
    f4 acc[2][2];
    acc[0][0] = fz; acc[0][1] = fz; acc[1][0] = fz; acc[1][1] = fz;
    #pragma unroll
    for (int kk = 0; kk < 4; ++kk) {
      int k0 = kk * 32;
      bf8 a0 = ldsFrag(Bm, iband * 64 + r0,      k0, 256);
      bf8 a1 = ldsFrag(Bm, iband * 64 + r0 + 16, k0, 256);
      bf8 b0 = ldsFrag(Yl, c0,      k0, 256);
      bf8 b1 = ldsFrag(Yl, c0 + 16, k0, 256);
      acc[0][0] = MFMA(a0, b0, acc[0][0]); acc[0][1] = MFMA(a0, b1, acc[0][1]);
      acc[1][0] = MFMA(a1, b0, acc[1][0]); acc[1][1] = MFMA(a1, b1, acc[1][1]);
    }
    #pragma unroll
    for (int i = 0; i < 2; ++i)
      #pragma unroll
      for (int j = 0; j < 2; ++j)
        #pragma unroll
        for (int r = 0; r < 4; ++r)
          ldsPut(El, r0 + i * 16 + lr + r, c0 + j * 16 + lc, 256, f2bf(acc[i][j][r]));
  }
  __syncthreads();
  { float invs = rsqrtf(normAg[b]);
    int r0 = (w >> 2) * 32, c0 = (w & 3) * 64;
    f4 acc[2][4];
    #pragma unroll
    for (int i = 0; i < 2; ++i)
      #pragma unroll
      for (int j = 0; j < 4; ++j) acc[i][j] = fz;
    #pragma unroll
    for (int kk = 0; kk < 4; ++kk) {
      int k0 = kk * 32;
      bf8 a0 = ldsFrag(El, r0,      k0, 256);
      bf8 a1 = ldsFrag(El, r0 + 16, k0, 256);
      bf8 b0 = ldsFrag(Bm, c0,      k0, 256);
      bf8 b1 = ldsFrag(Bm, c0 + 16, k0, 256);
      bf8 b2 = ldsFrag(Bm, c0 + 32, k0, 256);
      bf8 b3 = ldsFrag(Bm, c0 + 48, k0, 256);
      acc[0][0] = MFMA(a0, b0, acc[0][0]); acc[0][1] = MFMA(a0, b1, acc[0][1]);
      acc[0][2] = MFMA(a0, b2, acc[0][2]); acc[0][3] = MFMA(a0, b3, acc[0][3]);
      acc[1][0] = MFMA(a1, b0, acc[1][0]); acc[1][1] = MFMA(a1, b1, acc[1][1]);
      acc[1][2] = MFMA(a1, b2, acc[1][2]); acc[1][3] = MFMA(a1, b3, acc[1][3]);
    }
    #pragma unroll
    for (int i = 0; i < 2; ++i)
      #pragma unroll
      for (int r = 0; r < 4; ++r) {
        int il = r0 + i * 16 + lr + r;
        int ig = iband * 64 + il;
        float bs = g2[ig] * rsqrtf(v2[ig] + 1e-5f);
        float al = bs * rcw[ig];
        float be = (be2[ig] - m2[ig] * bs) * rcw[ig] + rcb[ig];
        #pragma unroll
        for (int j = 0; j < 4; ++j) {
          int jg = c0 + j * 16 + lc;
          sp[(size_t)b * 65536 + ig * 256 + jg] = f2bf(acc[i][j][r] * invs * al + be);
        }
      }
  }
}

// =====================================================================
// K5: logits[b][r] += s_post[b][:] . fc_w[r][:]
// =====================================================================
extern __shared__ char smfc[];
__global__ __launch_bounds__(512) void k_fc(const u16* __restrict__ sp,
                                            const float* __restrict__ fcw,
                                            float* __restrict__ logits){
  int kc = blockIdx.x >> 1, rh = blockIdx.x & 1;
  int k0 = kc * 256, rbase = rh * 128;
  char* Al = smfc;
  char* Bl = smfc + 32768;
  int t = threadIdx.x;
  { int row = t >> 3, q = t & 7;
    #pragma unroll
    for (int j = 0; j < 4; ++j) {
      int c16 = q + j * 8;
      bf8 v = *(const bf8*)(sp + (size_t)row * 65536 + k0 + c16 * 8);
      int ph = c16 ^ (row & 7);
      *(bf8*)(Al + row * 512 + ph * 16) = v;
    } }
  { int lane16 = t & 15;
    #pragma unroll
    for (int pass = 0; pass < 4; ++pass) {
      int row = (t >> 4) + pass * 32;
      #pragma unroll
      for (int j = 0; j < 4; ++j) {
        int k = lane16 * 4 + j * 64;
        float4 v = *(const float4*)(fcw + (size_t)(rbase + row) * 65536 + k0 + k);
        int off = (k * 2) ^ ((row & 7) << 4);
        *(u32*)(Bl + row * 512 + off)     = pk2(v.x, v.y);
        *(u32*)(Bl + row * 512 + off + 4) = pk2(v.z, v.w);
      }
    } }
  __syncthreads();
  int w = t >> 6, l = t & 63, lc = l & 15, lr = (l >> 4) * 4;
  int r0 = (w >> 2) * 32, c0 = (w & 3) * 32;
  const f4 fz = {0.f, 0.f, 0.f, 0.f};
  f4 acc[2][2];
  acc[0][0] = fz; acc[0][1] = fz; acc[1][0] = fz; acc[1][1] = fz;
  #pragma unroll
  for (int kk = 0; kk < 8; ++kk) {
    int ks = kk * 32;
    bf8 a0 = ldsFrag(Al, r0,      ks, 512);
    bf8 a1 = ldsFrag(Al, r0 + 16, ks, 512);
    bf8 b0 = ldsFrag(Bl, c0,      ks, 512);
    bf8 b1 = ldsFrag(Bl, c0 + 16, ks, 512);
    acc[0][0] = MFMA(a0, b0, acc[0][0]); acc[0][1] = MFMA(a0, b1, acc[0][1]);
    acc[1][0] = MFMA(a1, b0, acc[1][0]); acc[1][1] = MFMA(a1, b1, acc[1][1]);
  }
  #pragma unroll
  for (int i = 0; i < 2; ++i)
    #pragma unroll
    for (int j = 0; j < 2; ++j)
      #pragma unroll
      for (int r = 0; r < 4; ++r) {
        int row = r0 + i * 16 + lr + r;
        int col = rbase + c0 + j * 16 + lc;
        atomicAdd(logits + row * 256 + col, acc[i][j][r]);
      }
}

// =====================================================================
// K7: out = x * sigmoid(logits + fc_b)
// =====================================================================
__global__ __launch_bounds__(256) void k_mul(const float* __restrict__ x,
                                             const float* __restrict__ logits,
                                             const float* __restrict__ fcb,
                                             float* __restrict__ out, int n4){
  int i = blockIdx.x * 256 + threadIdx.x;
  int str = gridDim.x * 256;
  for (; i < n4; i += str) {
    int e = i << 2;
    int b = e >> 18;
    int hw = e & 255;
    float4 xv = ((const float4*)x)[i];
    float4 lg = *(const float4*)(logits + (b << 8) + hw);
    float4 fb = *(const float4*)(fcb + hw);
    float4 o;
    o.x = xv.x / (1.f + expf(-(lg.x + fb.x)));
    o.y = xv.y / (1.f + expf(-(lg.y + fb.y)));
    o.z = xv.z / (1.f + expf(-(lg.z + fb.z)));
    o.w = xv.w / (1.f + expf(-(lg.w + fb.w)));
    ((float4*)out)[i] = o;
  }
}

// =====================================================================
extern "C" void kernel_launch(void* const* d_in, const int* in_sizes, int n_in,
                              void* d_out, int out_size, void* d_ws, size_t ws_size,
                              hipStream_t stream){
  const float* x   = (const float*)d_in[0];
  const float* wdr = (const float*)d_in[1];
  const float* bdr = (const float*)d_in[2];
  const float* g1  = (const float*)d_in[3];
  const float* be1 = (const float*)d_in[4];
  const float* m1  = (const float*)d_in[5];
  const float* v1  = (const float*)d_in[6];
  const float* g2  = (const float*)d_in[7];
  const float* be2 = (const float*)d_in[8];
  const float* m2  = (const float*)d_in[9];
  const float* v2  = (const float*)d_in[10];
  const float* rcw = (const float*)d_in[11];
  const float* rcb = (const float*)d_in[12];
  const float* fcw = (const float*)d_in[13];
  const float* fcb = (const float*)d_in[14];
  float* out = (float*)d_out;
  char* ws = (char*)d_ws;
  u16*   Wg  = (u16*)(ws);                          // 4 MB
  u16*   WTg = (u16*)(ws + (4u  << 20));            // 4 MB
  u16*   yfg = (u16*)(ws + (8u  << 20));            // 2 MB
  float* nAg = (float*)(ws + (10u << 20));          // 256 B
  u16*   wpr = (u16*)(ws + (10u << 20) + 4096);     // 256 KB
  u16*   spg = (u16*)(ws + (11u << 20));            // 8 MB
  float* lgt = (float*)(ws + (20u << 20));          // 64 KB

  hipFuncSetAttribute((const void*)k_ns,     hipFuncAttributeMaxDynamicSharedMemorySize, 163840);
  hipFuncSetAttribute((const void*)k_expand, hipFuncAttributeMaxDynamicSharedMemorySize, 114688);
  hipFuncSetAttribute((const void*)k_fc,     hipFuncAttributeMaxDynamicSharedMemorySize, 98304);

  k_prep  <<<256,  256, 0,      stream>>>(wdr, lgt, wpr);
  k_conv  <<<512,  512, 0,      stream>>>(wpr, x, bdr, g1, be1, m1, v1, Wg, WTg);
  k_ns    <<<64,   512, 163840, stream>>>(WTg, yfg, nAg);
  k_expand<<<256,  512, 114688, stream>>>(Wg, yfg, nAg, g2, be2, m2, v2, rcw, rcb, spg);
  k_fc    <<<512,  512, 98304,  stream>>>(spg, fcw, lgt);
  k_mul   <<<2048, 256, 0,      stream>>>(x, lgt, fcb, out, 4194304);
}

// Round 4
// 113.742 us; speedup vs baseline: 1.2852x; 1.0168x over previous
//
#include <hip/hip_runtime.h>

typedef unsigned short u16;
typedef unsigned int   u32;
typedef __attribute__((ext_vector_type(8))) short bf8;   // 8 x bf16 (4 VGPRs)
typedef __attribute__((ext_vector_type(4))) float f4;    // 4 x f32 accumulator
typedef __attribute__((ext_vector_type(16))) float f16f; // 16 x f32 accumulator (32x32 MFMA)

#define MFMA(a,b,c)   __builtin_amdgcn_mfma_f32_16x16x32_bf16(a,b,c,0,0,0)
#define MFMA32(a,b,c) __builtin_amdgcn_mfma_f32_32x32x16_bf16(a,b,c,0,0,0)

__device__ __forceinline__ u16 f2bf(float f){
  u32 u = __float_as_uint(f);
  u += 0x7fffu + ((u >> 16) & 1u);          // RNE
  return (u16)(u >> 16);
}
__device__ __forceinline__ float bf2f(u16 h){ return __uint_as_float(((u32)h) << 16); }
__device__ __forceinline__ u32 pk2(float a, float b){ return (u32)f2bf(a) | ((u32)f2bf(b) << 16); }

__device__ __forceinline__ void glds16(const u16* g, u16* l){
  __builtin_amdgcn_global_load_lds((const __attribute__((address_space(1))) u32*)g,
                                   (__attribute__((address_space(3))) u32*)l, 16, 0, 0);
}

// ---- swizzled LDS bf16 matrix helpers (16x16 path) ----
__device__ __forceinline__ bf8 ldsFrag(const char* m, int row0, int k0, int pitch){
  int l = threadIdx.x & 63;
  int r = row0 + (l & 15);
  int kb = ((k0 + ((l >> 4) << 3)) << 1) ^ ((r & 7) << 4);
  return *(const bf8*)(m + r * pitch + kb);
}
__device__ __forceinline__ void ldsPut(char* m, int row, int col, int pitch, u16 v){
  int kb = (col << 1) ^ ((row & 7) << 4);
  *(u16*)(m + row * pitch + kb) = v;
}

// ---- k_ns helpers: pitch-256B rows, chunk swizzle (row&15)<<4 ----
__device__ __forceinline__ bf8 fragNS(const char* m, int r0, int ks, int l){
  int r = r0 + (l & 31);
  int kb = ((ks << 5) + ((l >> 5) << 4)) ^ ((r & 15) << 4);
  return *(const bf8*)(m + r * 256 + kb);
}
__device__ __forceinline__ bf8 fragWT(const char* m, int r0, int ks, int l){
  int r = r0 + (l & 31);
  int kb = ((ks << 5) + ((l >> 5) << 4)) ^ ((r & 15) << 4);
  return *(const bf8*)(m + r * 512 + kb);
}
__device__ __forceinline__ char* nsAddr(char* m, int row, int col4){
  return m + row * 256 + ((col4 << 1) ^ ((row & 15) << 4));
}

// 64x64 matmul pass: acc += A[R0.., :] @ Bsym[C0.., :]^T
__device__ __forceinline__ void mmPass(const char* A, const char* B, f16f (&acc)[2][2],
                                       int R0, int C0, int l){
  #pragma unroll
  for (int ks = 0; ks < 8; ++ks){
    bf8 a0 = fragNS(A, R0,      ks, l);
    bf8 a1 = fragNS(A, R0 + 32, ks, l);
    bf8 b0 = fragNS(B, C0,      ks, l);
    bf8 b1 = fragNS(B, C0 + 32, ks, l);
    acc[0][0] = MFMA32(a0, b0, acc[0][0]); acc[0][1] = MFMA32(a0, b1, acc[0][1]);
    acc[1][0] = MFMA32(a1, b0, acc[1][0]); acc[1][1] = MFMA32(a1, b1, acc[1][1]);
  }
}

// write 64x64 tile transposed (valid by symmetry), vectorized b64 stores.
__device__ __forceinline__ void writeTile(char* D, const f16f (&acc)[2][2], int R0, int C0, int l,
                                          float scale, float dval, const uint2* adv){
  #pragma unroll
  for (int ri = 0; ri < 2; ++ri)
  #pragma unroll
  for (int ci = 0; ci < 2; ++ci)
  #pragma unroll
  for (int g = 0; g < 4; ++g){
    int srow = C0 + ci * 32 + (l & 31);
    int scol = R0 + ri * 32 + g * 8 + ((l >> 5) << 2);
    float v[4];
    #pragma unroll
    for (int q = 0; q < 4; ++q){
      float x = scale * acc[ri][ci][g * 4 + q];
      x += ((scol + q) == srow) ? dval : 0.f;
      v[q] = x;
    }
    if (adv){
      uint2 ad = adv[(ri * 2 + ci) * 4 + g];
      v[0] += 1.5f * bf2f((u16)ad.x);
      v[1] += 1.5f * bf2f((u16)(ad.x >> 16));
      v[2] += 1.5f * bf2f((u16)ad.y);
      v[3] += 1.5f * bf2f((u16)(ad.y >> 16));
    }
    *(uint2*)nsAddr(D, srow, scol) = make_uint2(pk2(v[0], v[1]), pk2(v[2], v[3]));
  }
}

// =====================================================================
// K_prep: zero logits + convert w_dr -> bf16 pre-swizzled per-chunk LDS image
// =====================================================================
__global__ __launch_bounds__(256) void k_prep(const float* __restrict__ wdr,
                                              float* __restrict__ logits,
                                              u16* __restrict__ prep){
  int i = blockIdx.x * 256 + threadIdx.x;   // grid 256 -> 65536 threads
  if (i < 16384) logits[i] = 0.f;
  #pragma unroll
  for (int j = 0; j < 2; ++j){
    int e = i + j * 65536;
    int chunk = e >> 13, rem = e & 8191, d = rem >> 6, cb2 = rem & 63;
    int c = ((cb2 * 2) ^ ((d & 7) << 4)) >> 1;
    prep[e] = f2bf(wdr[d * 1024 + chunk * 64 + c]);
  }
}

// =====================================================================
// K1: 1x1 conv GEMM + BN1 + ReLU, center over d, scale 1/sqrt(128),
//     write W [b][hw][d] and WT [b][d][hw] (bf16)
// grid 512 = 64 b x 8 hw-blocks of 32; 512 threads (8 waves);
// counted-vmcnt pipeline: A via global_load_lds (2 bufs), B reg-staged (2 bufs),
// raw s_barrier (no vmcnt(0) drain in main loop).
// =====================================================================
__global__ __launch_bounds__(512) void k_conv(
    const u16* __restrict__ wprep, const float* __restrict__ x, const float* __restrict__ bdr,
    const float* __restrict__ g1, const float* __restrict__ be1,
    const float* __restrict__ m1, const float* __restrict__ v1,
    u16* __restrict__ Wg, u16* __restrict__ WTg){
  __shared__ union {
    struct { u16 A[2][8192]; u16 Bt[2][2048]; } s;
    struct { float y[128 * 33]; float musum[512]; float mu[32]; } e;
  } sm;
  int t = threadIdx.x;
  int b = blockIdx.x >> 3, hw0 = (blockIdx.x & 7) * 32;
  const float* xb = x + (size_t)b * 262144 + hw0;

  int w = t >> 6, l = t & 63;
  int d0 = (w >> 1) * 32, hh = (w & 1) * 16;
  int lc = l & 15, lr = (l >> 4) * 4;

  const f4 fz = {0.f, 0.f, 0.f, 0.f};
  f4 acc[2]; acc[0] = fz; acc[1] = fz;

  int cp = t >> 5, hwl = t & 31;
  int bo0 = (4 * cp) ^ ((hwl & 7) << 4);
  int bo1 = (4 * cp + 64) ^ ((hwl & 7) << 4);

  // prologue: issue A(0), A(1) via global_load_lds; issue B(0) -> regs
  glds16(wprep + t * 8,        sm.s.A[0] + t * 8);
  glds16(wprep + 4096 + t * 8, sm.s.A[0] + 4096 + t * 8);
  glds16(wprep + 8192 + t * 8,        sm.s.A[1] + t * 8);
  glds16(wprep + 8192 + 4096 + t * 8, sm.s.A[1] + 4096 + t * 8);
  float br0 = xb[(size_t)(2 * cp)      * 256 + hwl];
  float br1 = xb[(size_t)(2 * cp + 1)  * 256 + hwl];
  float br2 = xb[(size_t)(2 * cp + 32) * 256 + hwl];
  float br3 = xb[(size_t)(2 * cp + 33) * 256 + hwl];

  #pragma unroll
  for (int k = 0; k < 16; ++k){
    // a: issue A(k+1) (k>=1; k==0's A(1) already issued in prologue)
    if (k >= 1 && k < 15){
      const u16* src = wprep + (k + 1) * 8192;
      glds16(src + t * 8,        sm.s.A[(k + 1) & 1] + t * 8);
      glds16(src + 4096 + t * 8, sm.s.A[(k + 1) & 1] + 4096 + t * 8);
    }
    // b: issue B(k+1) -> regs
    float nb0 = 0.f, nb1 = 0.f, nb2 = 0.f, nb3 = 0.f;
    if (k < 15){
      int c0 = (k + 1) * 64;
      nb0 = xb[(size_t)(c0 + 2 * cp)      * 256 + hwl];
      nb1 = xb[(size_t)(c0 + 2 * cp + 1)  * 256 + hwl];
      nb2 = xb[(size_t)(c0 + 2 * cp + 32) * 256 + hwl];
      nb3 = xb[(size_t)(c0 + 2 * cp + 33) * 256 + hwl];
    }
    // c: counted wait -- retires A(k), B(k); keeps A(k+1), B(k+1) in flight
    __builtin_amdgcn_sched_barrier(0);
    if (k == 0)       asm volatile("s_waitcnt vmcnt(4)" ::: "memory");
    else if (k == 15) asm volatile("s_waitcnt vmcnt(0)" ::: "memory");
    else              asm volatile("s_waitcnt vmcnt(6)" ::: "memory");
    __builtin_amdgcn_sched_barrier(0);
    // d: write B(k) regs -> LDS
    *(u32*)((char*)sm.s.Bt[k & 1] + hwl * 128 + bo0) = pk2(br0, br1);
    *(u32*)((char*)sm.s.Bt[k & 1] + hwl * 128 + bo1) = pk2(br2, br3);
    // e: lgkm drain + raw barrier (A(k) in LDS + B(k) writes visible to all waves)
    asm volatile("s_waitcnt lgkmcnt(0)" ::: "memory");
    __builtin_amdgcn_sched_barrier(0);
    __builtin_amdgcn_s_barrier();
    __builtin_amdgcn_sched_barrier(0);
    // f: MFMA on chunk k
    #pragma unroll
    for (int ks = 0; ks < 2; ++ks){
      int k0 = ks * 32;
      bf8 a0 = ldsFrag((const char*)sm.s.A[k & 1], d0,      k0, 128);
      bf8 a1 = ldsFrag((const char*)sm.s.A[k & 1], d0 + 16, k0, 128);
      bf8 b0 = ldsFrag((const char*)sm.s.Bt[k & 1], hh, k0, 128);
      acc[0] = MFMA(a0, b0, acc[0]);
      acc[1] = MFMA(a1, b0, acc[1]);
    }
    // g: raw barrier (protect A/B buffer reuse by next iter's issues)
    __builtin_amdgcn_sched_barrier(0);
    __builtin_amdgcn_s_barrier();
    __builtin_amdgcn_sched_barrier(0);
    // rotate B regs
    br0 = nb0; br1 = nb1; br2 = nb2; br3 = nb3;
  }
  __syncthreads();

  // epilogue: BN1 + ReLU -> y stage (f32, pitch 33)
  #pragma unroll
  for (int i = 0; i < 2; ++i)
    #pragma unroll
    for (int r = 0; r < 4; ++r){
      int d = d0 + i * 16 + lr + r;
      float s1 = g1[d] * rsqrtf(v1[d] + 1e-5f);
      float t1 = (bdr[d] - m1[d]) * s1 + be1[d];
      int hwp = hh + lc;
      sm.e.y[d * 33 + hwp] = fmaxf(acc[i][r] * s1 + t1, 0.f);
    }
  __syncthreads();
  { // column means over d
    int part = t >> 5, col = t & 31;
    float s = 0.f;
    #pragma unroll
    for (int i2 = 0; i2 < 8; ++i2) s += sm.e.y[(part * 8 + i2) * 33 + col];
    sm.e.musum[part * 32 + col] = s;
  }
  __syncthreads();
  if (t < 32){
    float m = 0.f;
    #pragma unroll
    for (int p = 0; p < 16; ++p) m += sm.e.musum[p * 32 + t];
    sm.e.mu[t] = m * (1.0f / 128.0f);
  }
  __syncthreads();
  const float ISM = 0.08838834764831845f;   // 1/sqrt(128)
  { // W [b][hw][d]
    int hwp = t >> 4, dc = (t & 15) * 8;
    float muv = sm.e.mu[hwp];
    u32 q[4];
    #pragma unroll
    for (int jj = 0; jj < 4; ++jj){
      float a = (sm.e.y[(dc + 2 * jj)     * 33 + hwp] - muv) * ISM;
      float c = (sm.e.y[(dc + 2 * jj + 1) * 33 + hwp] - muv) * ISM;
      q[jj] = pk2(a, c);
    }
    *(uint4*)(Wg + ((size_t)(b * 256 + hw0 + hwp) * 128 + dc)) = make_uint4(q[0], q[1], q[2], q[3]);
  }
  { // WT [b][d][hw]
    int d = t >> 2, hc = (t & 3) * 8;
    u32 q[4];
    #pragma unroll
    for (int jj = 0; jj < 4; ++jj){
      int h0 = hc + 2 * jj, h1 = hc + 2 * jj + 1;
      float a = (sm.e.y[d * 33 + h0] - sm.e.mu[h0]) * ISM;
      float c = (sm.e.y[d * 33 + h1] - sm.e.mu[h1]) * ISM;
      q[jj] = pk2(a, c);
    }
    *(uint4*)(WTg + ((size_t)(b * 128 + d) * 256 + hw0 + hc)) = make_uint4(q[0], q[1], q[2], q[3]);
  }
}

// =====================================================================
// K3: per-batch Gram + Newton-Schulz (3 passes/iter, G register-resident,
//     32x32x16 MFMA, 64x64 tiles, b64 epilogues)
// =====================================================================
extern __shared__ char smns[];
__global__ __launch_bounds__(512, 2) void k_ns(const u16* __restrict__ WT,
                                               u16* __restrict__ yf, float* __restrict__ normAg){
  int b = blockIdx.x, t = threadIdx.x;
  char* Yb = smns;
  char* Zb = smns + 32768;
  char* T1 = smns + 65536;
  char* T2 = smns + 98304;
  char* T3 = smns + 131072;
  char* WTl = smns + 65536;
  char* G   = T3;
  float* trp = (float*)smns;

  int w = t >> 6, l = t & 63;
  int wq = w & 3;
  int R0 = (wq >> 1) * 64, C0 = (wq & 1) * 64;

  { const u16* src = WT + (size_t)b * 32768;
    int row = t >> 2, q = t & 3;
    #pragma unroll
    for (int j = 0; j < 8; ++j) {
      int c16 = q + j * 4;
      bf8 v = *(const bf8*)(src + row * 256 + c16 * 8);
      int ph = c16 ^ (row & 15);
      *(bf8*)(WTl + row * 512 + ph * 16) = v;
    }
  }
  if (t == 0) *trp = 0.f;
  __syncthreads();

  int R0g = (w & 3) * 32, C0g = (w >> 2) * 64;
  const f16f fz16 = {};
  f16f gac[2]; gac[0] = fz16; gac[1] = fz16;
  #pragma unroll
  for (int ks = 0; ks < 16; ++ks){
    bf8 a  = fragWT(WTl, R0g,      ks, l);
    bf8 b0 = fragWT(WTl, C0g,      ks, l);
    bf8 b1 = fragWT(WTl, C0g + 32, ks, l);
    gac[0] = MFMA32(a, b0, gac[0]);
    gac[1] = MFMA32(a, b1, gac[1]);
  }
  float tp = 0.f;
  #pragma unroll
  for (int ci = 0; ci < 2; ++ci)
    #pragma unroll
    for (int e = 0; e < 16; ++e){
      int row = R0g + (e & 3) + 8 * (e >> 2) + ((l >> 5) << 2);
      int col = C0g + ci * 32 + (l & 31);
      if (row == col) tp += gac[ci][e];
    }
  #pragma unroll
  for (int off = 32; off > 0; off >>= 1) tp += __shfl_down(tp, off);
  if (l == 0) atomicAdd(trp, tp);
  __syncthreads();

  float normA = fmaxf(*trp / 3.0f, 1e-12f);
  if (t == 0) normAg[b] = normA;
  float inv = 1.0f / normA;
  #pragma unroll
  for (int ci = 0; ci < 2; ++ci)
    #pragma unroll
    for (int g = 0; g < 4; ++g){
      int srow = C0g + ci * 32 + (l & 31);
      int scol = R0g + g * 8 + ((l >> 5) << 2);
      float v0 = gac[ci][g * 4 + 0] * inv, v1 = gac[ci][g * 4 + 1] * inv;
      float v2 = gac[ci][g * 4 + 2] * inv, v3 = gac[ci][g * 4 + 3] * inv;
      *(uint2*)nsAddr(G, srow, scol) = make_uint2(pk2(v0, v1), pk2(v2, v3));
    }
  __syncthreads();

  bf8 gA[8], gB[8];
  #pragma unroll
  for (int ks = 0; ks < 8; ++ks){
    gA[ks] = fragNS(G, C0,      ks, l);
    gB[ks] = fragNS(G, C0 + 32, ks, l);
  }
  { int row = t >> 2, q4 = t & 3;
    #pragma unroll
    for (int j = 0; j < 4; ++j){
      int c16 = q4 * 4 + j;
      int ph = c16 ^ (row & 15);
      bf8 gg = *(const bf8*)(G + row * 256 + ph * 16);
      bf8 yv, zv;
      #pragma unroll
      for (int e = 0; e < 8; ++e){
        int col = c16 * 8 + e;
        float y = -0.5f * bf2f((u16)gg[e]) + ((col == row) ? 1.5f : 0.f);
        yv[e] = (short)f2bf(y);
        zv[e] = (col == row) ? (short)f2bf(-0.5f) : (short)0;
      }
      *(bf8*)(Yb + row * 256 + ph * 16) = yv;
      *(bf8*)(Zb + row * 256 + ph * 16) = zv;
    }
  }
  __syncthreads();

  float z0 = 1.5f;
  for (int it = 0; it < 4; ++it){
    {
      f16f acc[2][2]; acc[0][0] = fz16; acc[0][1] = fz16; acc[1][0] = fz16; acc[1][1] = fz16;
      const char* As = (w < 4) ? Zb : Yb;
      #pragma unroll
      for (int ks = 0; ks < 8; ++ks){
        bf8 a0 = fragNS(As, R0,      ks, l);
        bf8 a1 = fragNS(As, R0 + 32, ks, l);
        acc[0][0] = MFMA32(a0, gA[ks], acc[0][0]); acc[0][1] = MFMA32(a0, gB[ks], acc[0][1]);
        acc[1][0] = MFMA32(a1, gA[ks], acc[1][0]); acc[1][1] = MFMA32(a1, gB[ks], acc[1][1]);
      }
      writeTile((w < 4) ? T1 : T3, acc, R0, C0, l, 1.0f, (w < 4) ? z0 : 0.f, nullptr);
    }
    __syncthreads();

    uint2 adv[16];
    {
      const char* addsrc = (w < 4) ? Zb : Yb;
      #pragma unroll
      for (int ri = 0; ri < 2; ++ri)
      #pragma unroll
      for (int ci = 0; ci < 2; ++ci)
      #pragma unroll
      for (int g = 0; g < 4; ++g){
        int srow = C0 + ci * 32 + (l & 31);
        int scol = R0 + ri * 32 + g * 8 + ((l >> 5) << 2);
        adv[(ri * 2 + ci) * 4 + g] = *(const uint2*)nsAddr((char*)addsrc, srow, scol);
      }
      if (w < 4){
        f16f acc[2][2]; acc[0][0] = fz16; acc[0][1] = fz16; acc[1][0] = fz16; acc[1][1] = fz16;
        mmPass(T1, Yb, acc, R0, C0, l);
        writeTile(T2, acc, R0, C0, l, -0.5f, 0.f, nullptr);
      }
    }
    __syncthreads();

    if ((w >= 4) || (it < 3)){
      f16f acc[2][2]; acc[0][0] = fz16; acc[0][1] = fz16; acc[1][0] = fz16; acc[1][1] = fz16;
      const char* A3 = (w < 4) ? T2 : T3;
      const char* B3 = (w < 4) ? T1 : T2;
      mmPass(A3, B3, acc, R0, C0, l);
      writeTile((w < 4) ? Zb : Yb, acc, R0, C0, l, 1.0f, 0.f, adv);
    }
    __syncthreads();
    z0 *= 1.5f;
  }

  { int row = t >> 2, q = t & 3;
    u16* dst = yf + (size_t)b * 16384 + row * 128;
    #pragma unroll
    for (int j = 0; j < 4; ++j) {
      int c16 = q * 4 + j;
      int ph = c16 ^ (row & 15);
      *(bf8*)(dst + c16 * 8) = *(const bf8*)(Yb + row * 256 + ph * 16);
    }
  }
}

// =====================================================================
// K4: S = W @ yf @ W^T / sqrt(normA), then BN2 row-affine + rc -> s_post bf16
// =====================================================================
extern __shared__ char smex[];
__global__ __launch_bounds__(512) void k_expand(
    const u16* __restrict__ Wg, const u16* __restrict__ yf, const float* __restrict__ normAg,
    const float* __restrict__ g2, const float* __restrict__ be2, const float* __restrict__ m2,
    const float* __restrict__ v2, const float* __restrict__ rcw, const float* __restrict__ rcb,
    u16* __restrict__ sp){
  int blk = blockIdx.x, b = blk >> 2, iband = blk & 3;
  char* Bm = smex;
  char* Yl = smex + 65536;
  char* El = smex + 98304;
  int t = threadIdx.x;
  { const u16* src = Wg + (size_t)b * 32768;
    int row = t >> 1, q = t & 1;
    #pragma unroll
    for (int j = 0; j < 8; ++j) {
      int c16 = q + j * 2;
      bf8 v = *(const bf8*)(src + row * 128 + c16 * 8);
      int ph = c16 ^ (row & 7);
      *(bf8*)(Bm + row * 256 + ph * 16) = v;
    } }
  { const u16* src = yf + (size_t)b * 16384;
    int row = t >> 2, q = t & 3;
    #pragma unroll
    for (int j = 0; j < 4; ++j) {
      int c16 = q + j * 4;
      bf8 v = *(const bf8*)(src + row * 128 + c16 * 8);
      int ph = c16 ^ (row & 7);
      *(bf8*)(Yl + row * 256 + ph * 16) = v;
    } }
  __syncthreads();
  int w = t >> 6, l = t & 63, lc = l & 15, lr = (l >> 4) * 4;
  const f4 fz = {0.f, 0.f, 0.f, 0.f};
  { int r0 = (w >> 2) * 32, c0 = (w & 3) * 32;
    f4 acc[2][2];
    acc[0][0] = fz; acc[0][1] = fz; acc[1][0] = fz; acc[1][1] = fz;
    #pragma unroll
    for (int kk = 0; kk < 4; ++kk) {
      int k0 = kk * 32;
      bf8 a0 = ldsFrag(Bm, iband * 64 + r0,      k0, 256);
      bf8 a1 = ldsFrag(Bm, iband * 64 + r0 + 16, k0, 256);
      bf8 b0 = ldsFrag(Yl, c0,      k0, 256);
      bf8 b1 = ldsFrag(Yl, c0 + 16, k0, 256);
      acc[0][0] = MFMA(a0, b0, acc[0][0]); acc[0][1] = MFMA(a0, b1, acc[0][1]);
      acc[1][0] = MFMA(a1, b0, acc[1][0]); acc[1][1] = MFMA(a1, b1, acc[1][1]);
    }
    #pragma unroll
    for (int i = 0; i < 2; ++i)
      #pragma unroll
      for (int j = 0; j < 2; ++j)
        #pragma unroll
        for (int r = 0; r < 4; ++r)
          ldsPut(El, r0 + i * 16 + lr + r, c0 + j * 16 + lc, 256, f2bf(acc[i][j][r]));
  }
  __syncthreads();
  { float invs = rsqrtf(normAg[b]);
    int r0 = (w >> 2) * 32, c0 = (w & 3) * 64;
    f4 acc[2][4];
    #pragma unroll
    for (int i = 0; i < 2; ++i)
      #pragma unroll
      for (int j = 0; j < 4; ++j) acc[i][j] = fz;
    #pragma unroll
    for (int kk = 0; kk < 4; ++kk) {
      int k0 = kk * 32;
      bf8 a0 = ldsFrag(El, r0,      k0, 256);
      bf8 a1 = ldsFrag(El, r0 + 16, k0, 256);
      bf8 b0 = ldsFrag(Bm, c0,      k0, 256);
      bf8 b1 = ldsFrag(Bm, c0 + 16, k0, 256);
      bf8 b2 = ldsFrag(Bm, c0 + 32, k0, 256);
      bf8 b3 = ldsFrag(Bm, c0 + 48, k0, 256);
      acc[0][0] = MFMA(a0, b0, acc[0][0]); acc[0][1] = MFMA(a0, b1, acc[0][1]);
      acc[0][2] = MFMA(a0, b2, acc[0][2]); acc[0][3] = MFMA(a0, b3, acc[0][3]);
      acc[1][0] = MFMA(a1, b0, acc[1][0]); acc[1][1] = MFMA(a1, b1, acc[1][1]);
      acc[1][2] = MFMA(a1, b2, acc[1][2]); acc[1][3] = MFMA(a1, b3, acc[1][3]);
    }
    #pragma unroll
    for (int i = 0; i < 2; ++i)
      #pragma unroll
      for (int r = 0; r < 4; ++r) {
        int il = r0 + i * 16 + lr + r;
        int ig = iband * 64 + il;
        float bs = g2[ig] * rsqrtf(v2[ig] + 1e-5f);
        float al = bs * rcw[ig];
        float be = (be2[ig] - m2[ig] * bs) * rcw[ig] + rcb[ig];
        #pragma unroll
        for (int j = 0; j < 4; ++j) {
          int jg = c0 + j * 16 + lc;
          sp[(size_t)b * 65536 + ig * 256 + jg] = f2bf(acc[i][j][r] * invs * al + be);
        }
      }
  }
}

// =====================================================================
// K5: logits[b][r] += s_post[b][:] . fc_w[r][:]
// =====================================================================
extern __shared__ char smfc[];
__global__ __launch_bounds__(512) void k_fc(const u16* __restrict__ sp,
                                            const float* __restrict__ fcw,
                                            float* __restrict__ logits){
  int kc = blockIdx.x >> 1, rh = blockIdx.x & 1;
  int k0 = kc * 256, rbase = rh * 128;
  char* Al = smfc;
  char* Bl = smfc + 32768;
  int t = threadIdx.x;
  { int row = t >> 3, q = t & 7;
    #pragma unroll
    for (int j = 0; j < 4; ++j) {
      int c16 = q + j * 8;
      bf8 v = *(const bf8*)(sp + (size_t)row * 65536 + k0 + c16 * 8);
      int ph = c16 ^ (row & 7);
      *(bf8*)(Al + row * 512 + ph * 16) = v;
    } }
  { int lane16 = t & 15;
    #pragma unroll
    for (int pass = 0; pass < 4; ++pass) {
      int row = (t >> 4) + pass * 32;
      #pragma unroll
      for (int j = 0; j < 4; ++j) {
        int k = lane16 * 4 + j * 64;
        float4 v = *(const float4*)(fcw + (size_t)(rbase + row) * 65536 + k0 + k);
        int off = (k * 2) ^ ((row & 7) << 4);
        *(u32*)(Bl + row * 512 + off)     = pk2(v.x, v.y);
        *(u32*)(Bl + row * 512 + off + 4) = pk2(v.z, v.w);
      }
    } }
  __syncthreads();
  int w = t >> 6, l = t & 63, lc = l & 15, lr = (l >> 4) * 4;
  int r0 = (w >> 2) * 32, c0 = (w & 3) * 32;
  const f4 fz = {0.f, 0.f, 0.f, 0.f};
  f4 acc[2][2];
  acc[0][0] = fz; acc[0][1] = fz; acc[1][0] = fz; acc[1][1] = fz;
  #pragma unroll
  for (int kk = 0; kk < 8; ++kk) {
    int ks = kk * 32;
    bf8 a0 = ldsFrag(Al, r0,      ks, 512);
    bf8 a1 = ldsFrag(Al, r0 + 16, ks, 512);
    bf8 b0 = ldsFrag(Bl, c0,      ks, 512);
    bf8 b1 = ldsFrag(Bl, c0 + 16, ks, 512);
    acc[0][0] = MFMA(a0, b0, acc[0][0]); acc[0][1] = MFMA(a0, b1, acc[0][1]);
    acc[1][0] = MFMA(a1, b0, acc[1][0]); acc[1][1] = MFMA(a1, b1, acc[1][1]);
  }
  #pragma unroll
  for (int i = 0; i < 2; ++i)
    #pragma unroll
    for (int j = 0; j < 2; ++j)
      #pragma unroll
      for (int r = 0; r < 4; ++r) {
        int row = r0 + i * 16 + lr + r;
        int col = rbase + c0 + j * 16 + lc;
        atomicAdd(logits + row * 256 + col, acc[i][j][r]);
      }
}

// =====================================================================
// K7: out = x * sigmoid(logits + fc_b)
// =====================================================================
__global__ __launch_bounds__(256) void k_mul(const float* __restrict__ x,
                                             const float* __restrict__ logits,
                                             const float* __restrict__ fcb,
                                             float* __restrict__ out, int n4){
  int i = blockIdx.x * 256 + threadIdx.x;
  int str = gridDim.x * 256;
  for (; i < n4; i += str) {
    int e = i << 2;
    int b = e >> 18;
    int hw = e & 255;
    float4 xv = ((const float4*)x)[i];
    float4 lg = *(const float4*)(logits + (b << 8) + hw);
    float4 fb = *(const float4*)(fcb + hw);
    float4 o;
    o.x = xv.x / (1.f + expf(-(lg.x + fb.x)));
    o.y = xv.y / (1.f + expf(-(lg.y + fb.y)));
    o.z = xv.z / (1.f + expf(-(lg.z + fb.z)));
    o.w = xv.w / (1.f + expf(-(lg.w + fb.w)));
    ((float4*)out)[i] = o;
  }
}

// =====================================================================
extern "C" void kernel_launch(void* const* d_in, const int* in_sizes, int n_in,
                              void* d_out, int out_size, void* d_ws, size_t ws_size,
                              hipStream_t stream){
  const float* x   = (const float*)d_in[0];
  const float* wdr = (const float*)d_in[1];
  const float* bdr = (const float*)d_in[2];
  const float* g1  = (const float*)d_in[3];
  const float* be1 = (const float*)d_in[4];
  const float* m1  = (const float*)d_in[5];
  const float* v1  = (const float*)d_in[6];
  const float* g2  = (const float*)d_in[7];
  const float* be2 = (const float*)d_in[8];
  const float* m2  = (const float*)d_in[9];
  const float* v2  = (const float*)d_in[10];
  const float* rcw = (const float*)d_in[11];
  const float* rcb = (const float*)d_in[12];
  const float* fcw = (const float*)d_in[13];
  const float* fcb = (const float*)d_in[14];
  float* out = (float*)d_out;
  char* ws = (char*)d_ws;
  u16*   Wg  = (u16*)(ws);                          // 4 MB
  u16*   WTg = (u16*)(ws + (4u  << 20));            // 4 MB
  u16*   yfg = (u16*)(ws + (8u  << 20));            // 2 MB
  float* nAg = (float*)(ws + (10u << 20));          // 256 B
  u16*   wpr = (u16*)(ws + (10u << 20) + 4096);     // 256 KB
  u16*   spg = (u16*)(ws + (11u << 20));            // 8 MB
  float* lgt = (float*)(ws + (20u << 20));          // 64 KB

  hipFuncSetAttribute((const void*)k_ns,     hipFuncAttributeMaxDynamicSharedMemorySize, 163840);
  hipFuncSetAttribute((const void*)k_expand, hipFuncAttributeMaxDynamicSharedMemorySize, 114688);
  hipFuncSetAttribute((const void*)k_fc,     hipFuncAttributeMaxDynamicSharedMemorySize, 98304);

  k_prep  <<<256,  256, 0,      stream>>>(wdr, lgt, wpr);
  k_conv  <<<512,  512, 0,      stream>>>(wpr, x, bdr, g1, be1, m1, v1, Wg, WTg);
  k_ns    <<<64,   512, 163840, stream>>>(WTg, yfg, nAg);
  k_expand<<<256,  512, 114688, stream>>>(Wg, yfg, nAg, g2, be2, m2, v2, rcw, rcb, spg);
  k_fc    <<<512,  512, 98304,  stream>>>(spg, fcw, lgt);
  k_mul   <<<2048, 256, 0,      stream>>>(x, lgt, fcb, out, 4194304);
}